// Round 2
// baseline (2179.210 us; speedup 1.0000x reference)
//
#include <hip/hip_runtime.h>
#include <hip/hip_bf16.h>
#include <cmath>

// CrossAttentionTransformerBlock: B=4, N=M=1024, C=768, H=12, HD=64, HID=3072
// Round 1: resubmit of round-0 baseline (previous bench hit GPUAcquisitionTimeout).
// bf16 MFMA GEMMs + f32 online-softmax attention.

typedef __bf16 bf16_t;
typedef __attribute__((ext_vector_type(8))) __bf16 bf16x8;
typedef __attribute__((ext_vector_type(4))) float f32x4;

#define NTOK 4096          // B*N rows
#define SCALE_ATTN 0.125f  // HD^-0.5

// ---------------- f32 -> bf16 conversion ----------------
__global__ void cvt_kernel(const float* __restrict__ src, bf16_t* __restrict__ dst, int n) {
    int i = (blockIdx.x * blockDim.x + threadIdx.x) * 4;
    if (i + 3 < n) {
        float4 v = *(const float4*)(src + i);
        dst[i + 0] = (bf16_t)v.x;
        dst[i + 1] = (bf16_t)v.y;
        dst[i + 2] = (bf16_t)v.z;
        dst[i + 3] = (bf16_t)v.w;
    }
}

// ---------------- LayerNorm over C=768, f32 in -> bf16 out ----------------
__global__ __launch_bounds__(256) void ln_kernel(const float* __restrict__ X,
                                                 const float* __restrict__ w,
                                                 const float* __restrict__ b,
                                                 bf16_t* __restrict__ out) {
    int row = blockIdx.x, t = threadIdx.x;
    const float* x = X + (size_t)row * 768;
    float v0 = x[t], v1 = x[t + 256], v2 = x[t + 512];
    float s = v0 + v1 + v2;
    float s2 = v0 * v0 + v1 * v1 + v2 * v2;
#pragma unroll
    for (int off = 32; off > 0; off >>= 1) {
        s += __shfl_down(s, off);
        s2 += __shfl_down(s2, off);
    }
    __shared__ float as_[4], as2_[4];
    int wave = t >> 6;
    if ((t & 63) == 0) { as_[wave] = s; as2_[wave] = s2; }
    __syncthreads();
    float tot = as_[0] + as_[1] + as_[2] + as_[3];
    float tot2 = as2_[0] + as2_[1] + as2_[2] + as2_[3];
    float mu = tot * (1.f / 768.f);
    float var = tot2 * (1.f / 768.f) - mu * mu;
    float rstd = rsqrtf(var + 1e-6f);
    bf16_t* o = out + (size_t)row * 768;
    o[t]       = (bf16_t)((v0 - mu) * rstd * w[t]       + b[t]);
    o[t + 256] = (bf16_t)((v1 - mu) * rstd * w[t + 256] + b[t + 256]);
    o[t + 512] = (bf16_t)((v2 - mu) * rstd * w[t + 512] + b[t + 512]);
}

// ---------------- bf16 MFMA GEMM:  C[4096][N] = A[4096][K] @ W[N][K]^T ----------------
// MODE 0: f32 out (+opt bias); MODE 1: f32 out + bias + residual; MODE 2: bf16 out + bias + GELU
template <int MODE>
__global__ __launch_bounds__(256, 2) void gemm_kernel(const bf16_t* __restrict__ A,
                                                      const bf16_t* __restrict__ W,
                                                      const float* __restrict__ bias,
                                                      const float* __restrict__ res,
                                                      float* __restrict__ outF,
                                                      bf16_t* __restrict__ outB,
                                                      int K, int N) {
    __shared__ bf16_t Alds[128 * 64];
    __shared__ bf16_t Blds[128 * 64];
    const int tid = threadIdx.x;
    const int bm = blockIdx.y, bn = blockIdx.x;
    const int lane = tid & 63, wid = tid >> 6;
    const int wm = wid >> 1, wn = wid & 1;
    f32x4 acc[4][4] = {};

    const int sr = tid >> 1;        // staging row 0..127
    const int scb = (tid & 1) * 4;  // staging chunk base (chunks of 8 bf16)
    const bf16_t* gA = A + (size_t)(bm * 128 + sr) * K;
    const bf16_t* gB = W + (size_t)(bn * 128 + sr) * K;

    for (int k0 = 0; k0 < K; k0 += 64) {
        __syncthreads();
#pragma unroll
        for (int q = 0; q < 4; ++q) {
            int c = scb + q;
            uint4 da = *(const uint4*)(gA + k0 + c * 8);
            uint4 db = *(const uint4*)(gB + k0 + c * 8);
            int s = c ^ (sr & 7);  // T2 XOR swizzle (16B chunks)
            *(uint4*)&Alds[sr * 64 + s * 8] = da;
            *(uint4*)&Blds[sr * 64 + s * 8] = db;
        }
        __syncthreads();
#pragma unroll
        for (int kk = 0; kk < 2; ++kk) {
            bf16x8 av[4], bv[4];
#pragma unroll
            for (int i = 0; i < 4; ++i) {
                int rA = wm * 64 + i * 16 + (lane & 15);
                int cc = kk * 4 + (lane >> 4);
                av[i] = *(const bf16x8*)&Alds[rA * 64 + (cc ^ (rA & 7)) * 8];
                int rB = wn * 64 + i * 16 + (lane & 15);
                bv[i] = *(const bf16x8*)&Blds[rB * 64 + (cc ^ (rB & 7)) * 8];
            }
#pragma unroll
            for (int i = 0; i < 4; ++i)
#pragma unroll
                for (int j = 0; j < 4; ++j)
                    acc[i][j] = __builtin_amdgcn_mfma_f32_16x16x32_bf16(av[i], bv[j], acc[i][j], 0, 0, 0);
        }
    }
    // epilogue: C/D layout col=lane&15, row=(lane>>4)*4+p  (HW-verified mapping)
#pragma unroll
    for (int i = 0; i < 4; ++i) {
        int row0 = bm * 128 + wm * 64 + i * 16 + (lane >> 4) * 4;
#pragma unroll
        for (int j = 0; j < 4; ++j) {
            int col = bn * 128 + wn * 64 + j * 16 + (lane & 15);
            float bv_ = bias ? bias[col] : 0.f;
#pragma unroll
            for (int p = 0; p < 4; ++p) {
                size_t idx = (size_t)(row0 + p) * N + col;
                float v = acc[i][j][p] + bv_;
                if (MODE == 1) v += res[idx];
                if (MODE == 2) {
                    v = 0.5f * v * (1.f + erff(v * 0.70710678118654752f));
                    outB[idx] = (bf16_t)v;
                } else {
                    outF[idx] = v;
                }
            }
        }
    }
}

// ---------------- generic f32 attention, online softmax ----------------
// O[b,n, h*64+d] = softmax_m( scale * Q[b,h,n,:]·K[b,h,m,:] ) @ V[b,h,m,:]
// Q/K/V are rows of f32 GEMM outputs; per-head column offset = h*hs.
__global__ __launch_bounds__(256) void attn_kernel(const float* __restrict__ Qp,
                                                   const float* __restrict__ Kp,
                                                   const float* __restrict__ Vp,
                                                   bf16_t* __restrict__ Op,
                                                   int ldQ, int ldK, int ldV,
                                                   int hsQ, int hsK, int hsV,
                                                   float scale) {
    __shared__ float Qs[32][68];
    __shared__ float Kt[64][68];
    __shared__ float Vt[64][68];
    __shared__ float Ss[32][68];
    const int tid = threadIdx.x;
    const int qt = blockIdx.x;  // query tile (32 rows)
    const int bh = blockIdx.y;  // 0..47
    const int b = bh / 12, h = bh % 12;
    const float* Qbase = Qp + (size_t)(b * 1024 + qt * 32) * ldQ + h * hsQ;
    const float* Kbase = Kp + (size_t)(b * 1024) * ldK + h * hsK;
    const float* Vbase = Vp + (size_t)(b * 1024) * ldV + h * hsV;
    {
        int r = tid >> 3, c0 = (tid & 7) * 8;
        const float* srcq = Qbase + (size_t)r * ldQ + c0;
        *(float4*)&Qs[r][c0]     = *(const float4*)(srcq);
        *(float4*)&Qs[r][c0 + 4] = *(const float4*)(srcq + 4);
    }
    const int t8 = tid & 7, r = tid >> 3;
    float m_run = -1e30f, l_run = 0.f;
    float oacc[8] = {0, 0, 0, 0, 0, 0, 0, 0};
    const int kr = tid >> 2, kc = (tid & 3) * 16;

    for (int kt0 = 0; kt0 < 1024; kt0 += 64) {
        __syncthreads();  // protect Kt/Vt vs previous iteration's readers
        const float* ksrc = Kbase + (size_t)(kt0 + kr) * ldK + kc;
        const float* vsrc = Vbase + (size_t)(kt0 + kr) * ldV + kc;
#pragma unroll
        for (int q = 0; q < 4; ++q) {
            *(float4*)&Kt[kr][kc + q * 4] = *(const float4*)(ksrc + q * 4);
            *(float4*)&Vt[kr][kc + q * 4] = *(const float4*)(vsrc + q * 4);
        }
        __syncthreads();
        // scores: this thread owns keys j = t8 + 8*jj
        float sj[8] = {0, 0, 0, 0, 0, 0, 0, 0};
        for (int k = 0; k < 64; k += 4) {
            float4 q4 = *(const float4*)&Qs[r][k];
#pragma unroll
            for (int jj = 0; jj < 8; ++jj) {
                float4 k4 = *(const float4*)&Kt[t8 + 8 * jj][k];
                sj[jj] += q4.x * k4.x + q4.y * k4.y + q4.z * k4.z + q4.w * k4.w;
            }
        }
        float mloc = -1e30f;
#pragma unroll
        for (int jj = 0; jj < 8; ++jj) { sj[jj] *= scale; mloc = fmaxf(mloc, sj[jj]); }
#pragma unroll
        for (int off = 1; off < 8; off <<= 1) mloc = fmaxf(mloc, __shfl_xor(mloc, off));
        float mnew = fmaxf(m_run, mloc);
        float corr = expf(m_run - mnew);
        float psum = 0.f;
#pragma unroll
        for (int jj = 0; jj < 8; ++jj) {
            float p = expf(sj[jj] - mnew);
            psum += p;
            Ss[r][t8 + 8 * jj] = p;
        }
#pragma unroll
        for (int off = 1; off < 8; off <<= 1) psum += __shfl_xor(psum, off);
        l_run = l_run * corr + psum;
        m_run = mnew;
#pragma unroll
        for (int dd = 0; dd < 8; ++dd) oacc[dd] *= corr;
        __syncthreads();
        // PV: this thread owns output cols d = t8*8 .. t8*8+7
        for (int j = 0; j < 64; ++j) {
            float p = Ss[r][j];
            float4 va = *(const float4*)&Vt[j][t8 * 8];
            float4 vb = *(const float4*)&Vt[j][t8 * 8 + 4];
            oacc[0] += p * va.x; oacc[1] += p * va.y; oacc[2] += p * va.z; oacc[3] += p * va.w;
            oacc[4] += p * vb.x; oacc[5] += p * vb.y; oacc[6] += p * vb.z; oacc[7] += p * vb.w;
        }
    }
    float inv = 1.f / l_run;
    bf16x8 pack;
#pragma unroll
    for (int dd = 0; dd < 8; ++dd) pack[dd] = (bf16_t)(oacc[dd] * inv);
    *(bf16x8*)(Op + (size_t)(b * 1024 + qt * 32 + r) * 768 + h * 64 + t8 * 8) = pack;
}

// ------------------------------------------------------------------
extern "C" void kernel_launch(void* const* d_in, const int* in_sizes, int n_in,
                              void* d_out, int out_size, void* d_ws, size_t ws_size,
                              hipStream_t stream) {
    const float* x_in   = (const float*)d_in[0];
    const float* src_in = (const float*)d_in[1];
    const float* b_proj   = (const float*)d_in[4];
    const float* b_proj_s = (const float*)d_in[7];
    const float* b_cp     = (const float*)d_in[13];
    const float* b_cp_s   = (const float*)d_in[15];
    const float* mlp1_b   = (const float*)d_in[17];
    const float* mlp2_b   = (const float*)d_in[19];
    const float* mlp1s_b  = (const float*)d_in[21];
    const float* mlp2s_b  = (const float*)d_in[23];
    const float* ln1_w  = (const float*)d_in[24];
    const float* ln1_b  = (const float*)d_in[25];
    const float* ln1s_w = (const float*)d_in[26];
    const float* ln1s_b = (const float*)d_in[27];
    const float* lnc_w  = (const float*)d_in[28];
    const float* lnc_b  = (const float*)d_in[29];
    const float* lncs_w = (const float*)d_in[30];
    const float* lncs_b = (const float*)d_in[31];
    const float* ln2_w  = (const float*)d_in[32];
    const float* ln2_b  = (const float*)d_in[33];
    const float* ln2s_w = (const float*)d_in[34];
    const float* ln2s_b = (const float*)d_in[35];

    char* ws = (char*)d_ws;
    size_t off = 0;
    auto alloc = [&](size_t bytes) -> void* {
        void* p = ws + off;
        off = (off + bytes + 255) & ~(size_t)255;
        return p;
    };

    // bf16 weights: {idx in d_in, N, K}
    const int widx[14] = {2, 3, 5, 6, 8, 9, 10, 11, 12, 14, 16, 18, 20, 22};
    const int wN[14]   = {2304, 768, 2304, 768, 1536, 1536, 768, 768, 768, 768, 3072, 768, 3072, 768};
    const int wK[14]   = {768, 768, 768, 768, 768, 768, 768, 768, 768, 768, 768, 3072, 768, 3072};
    bf16_t* bw[14];
    for (int i = 0; i < 14; ++i) bw[i] = (bf16_t*)alloc((size_t)wN[i] * wK[i] * 2);

    float*  Tbig = (float*)alloc((size_t)NTOK * 3072 * 4);
    float*  Vx   = (float*)alloc((size_t)NTOK * 768 * 4);
    float*  Vs   = (float*)alloc((size_t)NTOK * 768 * 4);
    bf16_t* LN_A = (bf16_t*)alloc((size_t)NTOK * 768 * 2);
    bf16_t* LN_B = (bf16_t*)alloc((size_t)NTOK * 768 * 2);
    bf16_t* O_A  = (bf16_t*)alloc((size_t)NTOK * 768 * 2);
    bf16_t* O_B  = (bf16_t*)alloc((size_t)NTOK * 768 * 2);

    float* Xst = (float*)d_out;                       // x residual state == output 0
    float* Sst = (float*)d_out + (size_t)NTOK * 768;  // src residual state == output 1
    float*  QKx = Tbig;
    float*  QKs = Tbig + (size_t)NTOK * 1536;
    bf16_t* H_A = (bf16_t*)Tbig;                         // mlp hidden x (bf16)
    bf16_t* H_B = (bf16_t*)Tbig + (size_t)NTOK * 3072;   // mlp hidden src (bf16)

    // 1. convert weights to bf16
    for (int i = 0; i < 14; ++i) {
        int n = wN[i] * wK[i];
        cvt_kernel<<<(n / 4 + 255) / 256, 256, 0, stream>>>((const float*)d_in[widx[i]], bw[i], n);
    }

    const dim3 blk(256);
    auto gemm_grid = [](int N) { return dim3(N / 128, NTOK / 128); };

    // ---- x self-attention ----
    ln_kernel<<<NTOK, blk, 0, stream>>>(x_in, ln1_w, ln1_b, LN_A);
    gemm_kernel<0><<<gemm_grid(2304), blk, 0, stream>>>(LN_A, bw[0], nullptr, nullptr, Tbig, nullptr, 768, 2304);
    attn_kernel<<<dim3(32, 48), blk, 0, stream>>>(Tbig, Tbig + 768, Tbig + 1536, O_A,
                                                  2304, 2304, 2304, 64, 64, 64, SCALE_ATTN);
    gemm_kernel<1><<<gemm_grid(768), blk, 0, stream>>>(O_A, bw[1], b_proj, x_in, Xst, nullptr, 768, 768);

    // ---- src self-attention ----
    ln_kernel<<<NTOK, blk, 0, stream>>>(src_in, ln1s_w, ln1s_b, LN_A);
    gemm_kernel<0><<<gemm_grid(2304), blk, 0, stream>>>(LN_A, bw[2], nullptr, nullptr, Tbig, nullptr, 768, 2304);
    attn_kernel<<<dim3(32, 48), blk, 0, stream>>>(Tbig, Tbig + 768, Tbig + 1536, O_A,
                                                  2304, 2304, 2304, 64, 64, 64, SCALE_ATTN);
    gemm_kernel<1><<<gemm_grid(768), blk, 0, stream>>>(O_A, bw[3], b_proj_s, src_in, Sst, nullptr, 768, 768);

    // ---- cross attention ----
    ln_kernel<<<NTOK, blk, 0, stream>>>(Xst, lnc_w, lnc_b, LN_A);
    ln_kernel<<<NTOK, blk, 0, stream>>>(Sst, lncs_w, lncs_b, LN_B);
    gemm_kernel<0><<<gemm_grid(1536), blk, 0, stream>>>(LN_A, bw[4], nullptr, nullptr, QKx, nullptr, 768, 1536);
    gemm_kernel<0><<<gemm_grid(1536), blk, 0, stream>>>(LN_B, bw[5], nullptr, nullptr, QKs, nullptr, 768, 1536);
    gemm_kernel<0><<<gemm_grid(768), blk, 0, stream>>>(LN_A, bw[6], nullptr, nullptr, Vx, nullptr, 768, 768);
    gemm_kernel<0><<<gemm_grid(768), blk, 0, stream>>>(LN_B, bw[7], nullptr, nullptr, Vs, nullptr, 768, 768);
    // y   = softmax(q  · q_s) @ v_s : Q=qk_x[:, :64], K=qk_s[:, :64], V=v_s
    attn_kernel<<<dim3(32, 48), blk, 0, stream>>>(QKx, QKs, Vs, O_A,
                                                  1536, 1536, 768, 128, 128, 64, SCALE_ATTN);
    // y_s = softmax(k_s · kx ) @ v  : Q=qk_s[:, 64:], K=qk_x[:, 64:], V=v_x
    attn_kernel<<<dim3(32, 48), blk, 0, stream>>>(QKs + 64, QKx + 64, Vx, O_B,
                                                  1536, 1536, 768, 128, 128, 64, SCALE_ATTN);
    gemm_kernel<1><<<gemm_grid(768), blk, 0, stream>>>(O_A, bw[8], b_cp, Xst, Xst, nullptr, 768, 768);
    gemm_kernel<1><<<gemm_grid(768), blk, 0, stream>>>(O_B, bw[9], b_cp_s, Sst, Sst, nullptr, 768, 768);

    // ---- MLPs ----
    ln_kernel<<<NTOK, blk, 0, stream>>>(Xst, ln2_w, ln2_b, LN_A);
    ln_kernel<<<NTOK, blk, 0, stream>>>(Sst, ln2s_w, ln2s_b, LN_B);
    gemm_kernel<2><<<gemm_grid(3072), blk, 0, stream>>>(LN_A, bw[10], mlp1_b, nullptr, nullptr, H_A, 768, 3072);
    gemm_kernel<2><<<gemm_grid(3072), blk, 0, stream>>>(LN_B, bw[12], mlp1s_b, nullptr, nullptr, H_B, 768, 3072);
    gemm_kernel<1><<<gemm_grid(768), blk, 0, stream>>>(H_A, bw[11], mlp2_b, Xst, Xst, nullptr, 3072, 768);
    gemm_kernel<1><<<gemm_grid(768), blk, 0, stream>>>(H_B, bw[13], mlp2s_b, Sst, Sst, nullptr, 3072, 768);
}

// Round 4
// 897.190 us; speedup vs baseline: 2.4289x; 2.4289x over previous
//
#include <hip/hip_runtime.h>
#include <hip/hip_bf16.h>
#include <cmath>

// CrossAttentionTransformerBlock: B=4, N=M=1024, C=768, H=12, HD=64, HID=3072
// Round 3: resubmit of round-2 (MFMA flash-attention) after GPUAcquisitionTimeout.

typedef __bf16 bf16_t;
typedef __attribute__((ext_vector_type(8))) __bf16 bf16x8;
typedef __attribute__((ext_vector_type(4))) __bf16 bf16x4;
typedef __attribute__((ext_vector_type(4))) float f32x4;

#define NTOK 4096          // B*N rows
#define SCALE_ATTN 0.125f  // HD^-0.5

// ---------------- f32 -> bf16 conversion ----------------
__global__ void cvt_kernel(const float* __restrict__ src, bf16_t* __restrict__ dst, int n) {
    int i = (blockIdx.x * blockDim.x + threadIdx.x) * 4;
    if (i + 3 < n) {
        float4 v = *(const float4*)(src + i);
        dst[i + 0] = (bf16_t)v.x;
        dst[i + 1] = (bf16_t)v.y;
        dst[i + 2] = (bf16_t)v.z;
        dst[i + 3] = (bf16_t)v.w;
    }
}

// ---------------- LayerNorm over C=768, f32 in -> bf16 out ----------------
__global__ __launch_bounds__(256) void ln_kernel(const float* __restrict__ X,
                                                 const float* __restrict__ w,
                                                 const float* __restrict__ b,
                                                 bf16_t* __restrict__ out) {
    int row = blockIdx.x, t = threadIdx.x;
    const float* x = X + (size_t)row * 768;
    float v0 = x[t], v1 = x[t + 256], v2 = x[t + 512];
    float s = v0 + v1 + v2;
    float s2 = v0 * v0 + v1 * v1 + v2 * v2;
#pragma unroll
    for (int off = 32; off > 0; off >>= 1) {
        s += __shfl_down(s, off);
        s2 += __shfl_down(s2, off);
    }
    __shared__ float as_[4], as2_[4];
    int wave = t >> 6;
    if ((t & 63) == 0) { as_[wave] = s; as2_[wave] = s2; }
    __syncthreads();
    float tot = as_[0] + as_[1] + as_[2] + as_[3];
    float tot2 = as2_[0] + as2_[1] + as2_[2] + as2_[3];
    float mu = tot * (1.f / 768.f);
    float var = tot2 * (1.f / 768.f) - mu * mu;
    float rstd = rsqrtf(var + 1e-6f);
    bf16_t* o = out + (size_t)row * 768;
    o[t]       = (bf16_t)((v0 - mu) * rstd * w[t]       + b[t]);
    o[t + 256] = (bf16_t)((v1 - mu) * rstd * w[t + 256] + b[t + 256]);
    o[t + 512] = (bf16_t)((v2 - mu) * rstd * w[t + 512] + b[t + 512]);
}

// ---------------- bf16 MFMA GEMM:  C[4096][N] = A[4096][K] @ W[N][K]^T ----------------
// MODE 1: f32 out + bias + residual
// MODE 2: bf16 out + bias + GELU
// MODE 3: bf16 out (no bias)
// MODE 4: bf16 TRANSPOSED out: OT[col][4096] (no bias)
template <int MODE>
__global__ __launch_bounds__(256, 2) void gemm_kernel(const bf16_t* __restrict__ A,
                                                      const bf16_t* __restrict__ W,
                                                      const float* __restrict__ bias,
                                                      const float* __restrict__ res,
                                                      float* __restrict__ outF,
                                                      bf16_t* __restrict__ outB,
                                                      int K, int N) {
    __shared__ bf16_t Alds[128 * 64];
    __shared__ bf16_t Blds[128 * 64];
    const int tid = threadIdx.x;
    const int bm = blockIdx.y, bn = blockIdx.x;
    const int lane = tid & 63, wid = tid >> 6;
    const int wm = wid >> 1, wn = wid & 1;
    f32x4 acc[4][4] = {};

    const int sr = tid >> 1;        // staging row 0..127
    const int scb = (tid & 1) * 4;  // staging chunk base (chunks of 8 bf16)
    const bf16_t* gA = A + (size_t)(bm * 128 + sr) * K;
    const bf16_t* gB = W + (size_t)(bn * 128 + sr) * K;

    for (int k0 = 0; k0 < K; k0 += 64) {
        __syncthreads();
#pragma unroll
        for (int q = 0; q < 4; ++q) {
            int c = scb + q;
            uint4 da = *(const uint4*)(gA + k0 + c * 8);
            uint4 db = *(const uint4*)(gB + k0 + c * 8);
            int s = c ^ (sr & 7);  // T2 XOR swizzle (16B chunks)
            *(uint4*)&Alds[sr * 64 + s * 8] = da;
            *(uint4*)&Blds[sr * 64 + s * 8] = db;
        }
        __syncthreads();
#pragma unroll
        for (int kk = 0; kk < 2; ++kk) {
            bf16x8 av[4], bv[4];
#pragma unroll
            for (int i = 0; i < 4; ++i) {
                int rA = wm * 64 + i * 16 + (lane & 15);
                int cc = kk * 4 + (lane >> 4);
                av[i] = *(const bf16x8*)&Alds[rA * 64 + (cc ^ (rA & 7)) * 8];
                int rB = wn * 64 + i * 16 + (lane & 15);
                bv[i] = *(const bf16x8*)&Blds[rB * 64 + (cc ^ (rB & 7)) * 8];
            }
#pragma unroll
            for (int i = 0; i < 4; ++i)
#pragma unroll
                for (int j = 0; j < 4; ++j)
                    acc[i][j] = __builtin_amdgcn_mfma_f32_16x16x32_bf16(av[i], bv[j], acc[i][j], 0, 0, 0);
        }
    }
    // epilogue: C/D layout col=lane&15, row=(lane>>4)*4+p  (HW-verified mapping)
#pragma unroll
    for (int i = 0; i < 4; ++i) {
        int row0 = bm * 128 + wm * 64 + i * 16 + (lane >> 4) * 4;
#pragma unroll
        for (int j = 0; j < 4; ++j) {
            int col = bn * 128 + wn * 64 + j * 16 + (lane & 15);
            if (MODE == 4) {
                bf16x4 pk;
#pragma unroll
                for (int p = 0; p < 4; ++p) pk[p] = (bf16_t)acc[i][j][p];
                *(bf16x4*)&outB[(size_t)col * NTOK + row0] = pk;
            } else {
                float bv_ = (MODE == 3) ? 0.f : bias[col];
#pragma unroll
                for (int p = 0; p < 4; ++p) {
                    size_t idx = (size_t)(row0 + p) * N + col;
                    float v = acc[i][j][p] + bv_;
                    if (MODE == 1) {
                        outF[idx] = v + res[idx];
                    } else if (MODE == 2) {
                        v = 0.5f * v * (1.f + erff(v * 0.70710678118654752f));
                        outB[idx] = (bf16_t)v;
                    } else {  // MODE 3
                        outB[idx] = (bf16_t)v;
                    }
                }
            }
        }
    }
}

// ---------------- MFMA flash attention (bf16 in, bf16 out) ----------------
// O[b, q, h*64+d] = softmax_k( scale * Q[q,:]·K[k,:] ) @ V[k,:]
// Q: rows of [4096][ldQ] bf16, head base h*hsQ.  K likewise.
// VT: [768][4096] bf16 transposed V (row = h*64+d, col = token).
// Block: 64 q-rows, 4 waves x 16 rows. KV tiles of 64.
__global__ __launch_bounds__(256, 2) void attn_mfma_kernel(const bf16_t* __restrict__ Qp,
                                                           const bf16_t* __restrict__ Kp,
                                                           const bf16_t* __restrict__ VTp,
                                                           bf16_t* __restrict__ Op,
                                                           int ldQ, int ldK,
                                                           int hsQ, int hsK,
                                                           float scale) {
    __shared__ bf16_t Kl[64 * 64];
    __shared__ bf16_t Vl[64 * 64];
    __shared__ bf16_t Pl[4][16 * 64];
    const int tid = threadIdx.x, lane = tid & 63, w = tid >> 6;
    const int l15 = lane & 15, lh = lane >> 4;  // lh in 0..3
    const int q0 = blockIdx.x * 64;
    const int bh = blockIdx.y, b = bh / 12, h = bh % 12;

    // Q fragments (A-operand): row = q0 + w*16 + l15, k-chunks lh*8 (+32)
    const bf16_t* qptr = Qp + (size_t)(b * 1024 + q0 + w * 16 + l15) * ldQ + h * hsQ + lh * 8;
    bf16x8 qf0 = *(const bf16x8*)qptr;
    bf16x8 qf1 = *(const bf16x8*)(qptr + 32);

    f32x4 oacc[4] = {};
    float m_run[4], l_run[4];
#pragma unroll
    for (int p = 0; p < 4; ++p) { m_run[p] = -1e30f; l_run[p] = 0.f; }

    const int srow = tid >> 2;       // staging row 0..63
    const int sc0 = (tid & 3) * 2;   // 2 chunks of 8 bf16 each
    const bf16_t* kbase = Kp + (size_t)(b * 1024) * ldK + h * hsK;
    const bf16_t* vbase = VTp + (size_t)(h * 64 + srow) * NTOK + b * 1024;

    for (int kt = 0; kt < 1024; kt += 64) {
        __syncthreads();
        const bf16_t* krow = kbase + (size_t)(kt + srow) * ldK;
#pragma unroll
        for (int cc = 0; cc < 2; ++cc) {
            int c = sc0 + cc;
            int sw = (c ^ (srow & 7)) * 8;
            *(uint4*)&Kl[srow * 64 + sw] = *(const uint4*)(krow + c * 8);
            *(uint4*)&Vl[srow * 64 + sw] = *(const uint4*)(vbase + kt + c * 8);
        }
        __syncthreads();

        // QK^T: S[16 q x 64 keys] per wave = 4 key-tiles x 2 k-chunks
        f32x4 s[4] = {};
#pragma unroll
        for (int t = 0; t < 4; ++t) {
            int key = t * 16 + l15;
            bf16x8 kf0 = *(const bf16x8*)&Kl[key * 64 + ((lh ^ (key & 7)) * 8)];
            bf16x8 kf1 = *(const bf16x8*)&Kl[key * 64 + (((4 + lh) ^ (key & 7)) * 8)];
            s[t] = __builtin_amdgcn_mfma_f32_16x16x32_bf16(qf0, kf0, s[t], 0, 0, 0);
            s[t] = __builtin_amdgcn_mfma_f32_16x16x32_bf16(qf1, kf1, s[t], 0, 0, 0);
        }

        // online softmax: lane holds rows r=lh*4+p, key col = t*16+l15
#pragma unroll
        for (int p = 0; p < 4; ++p) {
            float v0 = s[0][p] * scale, v1 = s[1][p] * scale;
            float v2 = s[2][p] * scale, v3 = s[3][p] * scale;
            float mloc = fmaxf(fmaxf(v0, v1), fmaxf(v2, v3));
#pragma unroll
            for (int off = 1; off < 16; off <<= 1) mloc = fmaxf(mloc, __shfl_xor(mloc, off));
            float mnew = fmaxf(m_run[p], mloc);
            float corr = __expf(m_run[p] - mnew);
            float p0 = __expf(v0 - mnew), p1 = __expf(v1 - mnew);
            float p2 = __expf(v2 - mnew), p3 = __expf(v3 - mnew);
            float ps = p0 + p1 + p2 + p3;
#pragma unroll
            for (int off = 1; off < 16; off <<= 1) ps += __shfl_xor(ps, off);
            l_run[p] = l_run[p] * corr + ps;
            m_run[p] = mnew;
            oacc[0][p] *= corr; oacc[1][p] *= corr; oacc[2][p] *= corr; oacc[3][p] *= corr;
            // write P row r, cols t*16+l15 (swizzled 16B chunks)
            int r = lh * 4 + p;
            bf16_t* pr = &Pl[w][r * 64];
            int cb = l15 >> 3, ce = l15 & 7, rs = r & 7;
            pr[((0 + cb) ^ rs) * 8 + ce] = (bf16_t)p0;
            pr[((2 + cb) ^ rs) * 8 + ce] = (bf16_t)p1;
            pr[((4 + cb) ^ rs) * 8 + ce] = (bf16_t)p2;
            pr[((6 + cb) ^ rs) * 8 + ce] = (bf16_t)p3;
        }

        // PV: O[16 q x 64 d] += P[16 x 64] @ V[64 x 64]
#pragma unroll
        for (int kk = 0; kk < 2; ++kk) {
            bf16x8 pf = *(const bf16x8*)&Pl[w][l15 * 64 + (((kk * 4 + lh) ^ (l15 & 7)) * 8)];
#pragma unroll
            for (int dt = 0; dt < 4; ++dt) {
                int d = dt * 16 + l15;
                bf16x8 vf = *(const bf16x8*)&Vl[d * 64 + (((kk * 4 + lh) ^ (d & 7)) * 8)];
                oacc[dt] = __builtin_amdgcn_mfma_f32_16x16x32_bf16(pf, vf, oacc[dt], 0, 0, 0);
            }
        }
    }

    float inv[4];
#pragma unroll
    for (int p = 0; p < 4; ++p) inv[p] = 1.f / l_run[p];
#pragma unroll
    for (int dt = 0; dt < 4; ++dt) {
#pragma unroll
        for (int p = 0; p < 4; ++p) {
            int row = q0 + w * 16 + lh * 4 + p;
            int col = h * 64 + dt * 16 + l15;
            Op[(size_t)(b * 1024 + row) * 768 + col] = (bf16_t)(oacc[dt][p] * inv[p]);
        }
    }
}

// ------------------------------------------------------------------
extern "C" void kernel_launch(void* const* d_in, const int* in_sizes, int n_in,
                              void* d_out, int out_size, void* d_ws, size_t ws_size,
                              hipStream_t stream) {
    const float* x_in   = (const float*)d_in[0];
    const float* src_in = (const float*)d_in[1];
    const float* b_proj   = (const float*)d_in[4];
    const float* b_proj_s = (const float*)d_in[7];
    const float* b_cp     = (const float*)d_in[13];
    const float* b_cp_s   = (const float*)d_in[15];
    const float* mlp1_b   = (const float*)d_in[17];
    const float* mlp2_b   = (const float*)d_in[19];
    const float* mlp1s_b  = (const float*)d_in[21];
    const float* mlp2s_b  = (const float*)d_in[23];
    const float* ln1_w  = (const float*)d_in[24];
    const float* ln1_b  = (const float*)d_in[25];
    const float* ln1s_w = (const float*)d_in[26];
    const float* ln1s_b = (const float*)d_in[27];
    const float* lnc_w  = (const float*)d_in[28];
    const float* lnc_b  = (const float*)d_in[29];
    const float* lncs_w = (const float*)d_in[30];
    const float* lncs_b = (const float*)d_in[31];
    const float* ln2_w  = (const float*)d_in[32];
    const float* ln2_b  = (const float*)d_in[33];
    const float* ln2s_w = (const float*)d_in[34];
    const float* ln2s_b = (const float*)d_in[35];

    char* ws = (char*)d_ws;
    size_t off = 0;
    auto alloc = [&](size_t bytes) -> void* {
        void* p = ws + off;
        off = (off + bytes + 255) & ~(size_t)255;
        return p;
    };

    // bf16 weights: {idx in d_in, N, K}
    const int widx[14] = {2, 3, 5, 6, 8, 9, 10, 11, 12, 14, 16, 18, 20, 22};
    const int wN[14]   = {2304, 768, 2304, 768, 1536, 1536, 768, 768, 768, 768, 3072, 768, 3072, 768};
    const int wK[14]   = {768, 768, 768, 768, 768, 768, 768, 768, 768, 768, 768, 3072, 768, 3072};
    bf16_t* bw[14];
    for (int i = 0; i < 14; ++i) bw[i] = (bf16_t*)alloc((size_t)wN[i] * wK[i] * 2);

    // shared arena reused across the three phases (self-attn / cross-attn / mlp)
    bf16_t* arena = (bf16_t*)alloc((size_t)NTOK * 3072 * 2 * 2);  // 2x [4096][3072] bf16
    bf16_t* LN_A = (bf16_t*)alloc((size_t)NTOK * 768 * 2);
    bf16_t* LN_B = (bf16_t*)alloc((size_t)NTOK * 768 * 2);
    bf16_t* O_A  = (bf16_t*)alloc((size_t)NTOK * 768 * 2);
    bf16_t* O_B  = (bf16_t*)alloc((size_t)NTOK * 768 * 2);

    float* Xst = (float*)d_out;                       // x residual state == output 0
    float* Sst = (float*)d_out + (size_t)NTOK * 768;  // src residual state == output 1

    // phase-1 overlay: self-attention QK + VT
    bf16_t* SQK = arena;                               // [4096][1536]
    bf16_t* VTs = arena + (size_t)NTOK * 1536;         // [768][4096]
    // phase-2 overlay: cross attention
    bf16_t* QKx = arena;                               // [4096][1536]
    bf16_t* QKs = arena + (size_t)NTOK * 1536;         // [4096][1536]
    bf16_t* VxT = arena + (size_t)NTOK * 3072;         // [768][4096]
    bf16_t* VsT = arena + (size_t)NTOK * 3072 + (size_t)768 * NTOK;
    // phase-3 overlay: mlp hidden
    bf16_t* H_A = arena;                               // [4096][3072]
    bf16_t* H_B = arena + (size_t)NTOK * 3072;         // [4096][3072]

    // convert weights to bf16
    for (int i = 0; i < 14; ++i) {
        int n = wN[i] * wK[i];
        cvt_kernel<<<(n / 4 + 255) / 256, 256, 0, stream>>>((const float*)d_in[widx[i]], bw[i], n);
    }

    const dim3 blk(256);
    auto gemm_grid = [](int N) { return dim3(N / 128, NTOK / 128); };
    const dim3 attn_grid(16, 48);

    // ---- x self-attention ----
    ln_kernel<<<NTOK, blk, 0, stream>>>(x_in, ln1_w, ln1_b, LN_A);
    gemm_kernel<3><<<gemm_grid(1536), blk, 0, stream>>>(LN_A, bw[0], nullptr, nullptr, nullptr, SQK, 768, 1536);
    gemm_kernel<4><<<gemm_grid(768), blk, 0, stream>>>(LN_A, bw[0] + (size_t)1536 * 768, nullptr, nullptr, nullptr, VTs, 768, 768);
    attn_mfma_kernel<<<attn_grid, blk, 0, stream>>>(SQK, SQK + 768, VTs, O_A, 1536, 1536, 64, 64, SCALE_ATTN);
    gemm_kernel<1><<<gemm_grid(768), blk, 0, stream>>>(O_A, bw[1], b_proj, x_in, Xst, nullptr, 768, 768);

    // ---- src self-attention ----
    ln_kernel<<<NTOK, blk, 0, stream>>>(src_in, ln1s_w, ln1s_b, LN_A);
    gemm_kernel<3><<<gemm_grid(1536), blk, 0, stream>>>(LN_A, bw[2], nullptr, nullptr, nullptr, SQK, 768, 1536);
    gemm_kernel<4><<<gemm_grid(768), blk, 0, stream>>>(LN_A, bw[2] + (size_t)1536 * 768, nullptr, nullptr, nullptr, VTs, 768, 768);
    attn_mfma_kernel<<<attn_grid, blk, 0, stream>>>(SQK, SQK + 768, VTs, O_A, 1536, 1536, 64, 64, SCALE_ATTN);
    gemm_kernel<1><<<gemm_grid(768), blk, 0, stream>>>(O_A, bw[3], b_proj_s, src_in, Sst, nullptr, 768, 768);

    // ---- cross attention ----
    ln_kernel<<<NTOK, blk, 0, stream>>>(Xst, lnc_w, lnc_b, LN_A);
    ln_kernel<<<NTOK, blk, 0, stream>>>(Sst, lncs_w, lncs_b, LN_B);
    gemm_kernel<3><<<gemm_grid(1536), blk, 0, stream>>>(LN_A, bw[4], nullptr, nullptr, nullptr, QKx, 768, 1536);
    gemm_kernel<3><<<gemm_grid(1536), blk, 0, stream>>>(LN_B, bw[5], nullptr, nullptr, nullptr, QKs, 768, 1536);
    gemm_kernel<4><<<gemm_grid(768), blk, 0, stream>>>(LN_A, bw[6], nullptr, nullptr, nullptr, VxT, 768, 768);
    gemm_kernel<4><<<gemm_grid(768), blk, 0, stream>>>(LN_B, bw[7], nullptr, nullptr, nullptr, VsT, 768, 768);
    // y   = softmax(q · q_s) @ v_s : Q = qk_x[:, h*128..+64), K = qk_s[:, h*128..+64)
    attn_mfma_kernel<<<attn_grid, blk, 0, stream>>>(QKx, QKs, VsT, O_A, 1536, 1536, 128, 128, SCALE_ATTN);
    // y_s = softmax(k_s · kx) @ v  : Q = qk_s[:, h*128+64..), K = qk_x[:, h*128+64..)
    attn_mfma_kernel<<<attn_grid, blk, 0, stream>>>(QKs + 64, QKx + 64, VxT, O_B, 1536, 1536, 128, 128, SCALE_ATTN);
    gemm_kernel<1><<<gemm_grid(768), blk, 0, stream>>>(O_A, bw[8], b_cp, Xst, Xst, nullptr, 768, 768);
    gemm_kernel<1><<<gemm_grid(768), blk, 0, stream>>>(O_B, bw[9], b_cp_s, Sst, Sst, nullptr, 768, 768);

    // ---- MLPs ----
    ln_kernel<<<NTOK, blk, 0, stream>>>(Xst, ln2_w, ln2_b, LN_A);
    ln_kernel<<<NTOK, blk, 0, stream>>>(Sst, ln2s_w, ln2s_b, LN_B);
    gemm_kernel<2><<<gemm_grid(3072), blk, 0, stream>>>(LN_A, bw[10], mlp1_b, nullptr, nullptr, H_A, 768, 3072);
    gemm_kernel<2><<<gemm_grid(3072), blk, 0, stream>>>(LN_B, bw[12], mlp1s_b, nullptr, nullptr, H_B, 768, 3072);
    gemm_kernel<1><<<gemm_grid(768), blk, 0, stream>>>(H_A, bw[11], mlp2_b, Xst, Xst, nullptr, 3072, 768);
    gemm_kernel<1><<<gemm_grid(768), blk, 0, stream>>>(H_B, bw[13], mlp2s_b, Sst, Sst, nullptr, 3072, 768);
}

// Round 5
// 797.387 us; speedup vs baseline: 2.7329x; 1.1252x over previous
//
#include <hip/hip_runtime.h>
#include <hip/hip_bf16.h>
#include <cmath>

// CrossAttentionTransformerBlock: B=4, N=M=1024, C=768, H=12, HD=64, HID=3072
// Round 4->5: occupancy round. BN=64 GEMM for N=768 (grid 192->384), fused QKV
// GEMM (N=2304, dual-layout epilogue), single mega-cvt kernel.

typedef __bf16 bf16_t;
typedef __attribute__((ext_vector_type(8))) __bf16 bf16x8;
typedef __attribute__((ext_vector_type(4))) __bf16 bf16x4;
typedef __attribute__((ext_vector_type(4))) float f32x4;

#define NTOK 4096          // B*N rows
#define SCALE_ATTN 0.125f  // HD^-0.5

// ---------------- mega f32->bf16 conversion (14 segments, one launch) -------
struct CvtTab {
    const float* src[14];
    bf16_t* dst[14];
    int n[14];  // element counts, all multiples of 2048
};
__global__ __launch_bounds__(256) void cvt_all_kernel(CvtTab t) {
    int seg = blockIdx.y;
    int base = blockIdx.x * 2048 + threadIdx.x * 8;
    if (base >= t.n[seg]) return;
    const float* s = t.src[seg];
    float4 a = *(const float4*)(s + base);
    float4 b = *(const float4*)(s + base + 4);
    bf16x8 o;
    o[0] = (bf16_t)a.x; o[1] = (bf16_t)a.y; o[2] = (bf16_t)a.z; o[3] = (bf16_t)a.w;
    o[4] = (bf16_t)b.x; o[5] = (bf16_t)b.y; o[6] = (bf16_t)b.z; o[7] = (bf16_t)b.w;
    *(bf16x8*)(t.dst[seg] + base) = o;
}

// ---------------- LayerNorm over C=768, f32 in -> bf16 out ----------------
__global__ __launch_bounds__(256) void ln_kernel(const float* __restrict__ X,
                                                 const float* __restrict__ w,
                                                 const float* __restrict__ b,
                                                 bf16_t* __restrict__ out) {
    int row = blockIdx.x, t = threadIdx.x;
    const float* x = X + (size_t)row * 768;
    float v0 = x[t], v1 = x[t + 256], v2 = x[t + 512];
    float s = v0 + v1 + v2;
    float s2 = v0 * v0 + v1 * v1 + v2 * v2;
#pragma unroll
    for (int off = 32; off > 0; off >>= 1) {
        s += __shfl_down(s, off);
        s2 += __shfl_down(s2, off);
    }
    __shared__ float as_[4], as2_[4];
    int wave = t >> 6;
    if ((t & 63) == 0) { as_[wave] = s; as2_[wave] = s2; }
    __syncthreads();
    float tot = as_[0] + as_[1] + as_[2] + as_[3];
    float tot2 = as2_[0] + as2_[1] + as2_[2] + as2_[3];
    float mu = tot * (1.f / 768.f);
    float var = tot2 * (1.f / 768.f) - mu * mu;
    float rstd = rsqrtf(var + 1e-6f);
    bf16_t* o = out + (size_t)row * 768;
    o[t]       = (bf16_t)((v0 - mu) * rstd * w[t]       + b[t]);
    o[t + 256] = (bf16_t)((v1 - mu) * rstd * w[t + 256] + b[t + 256]);
    o[t + 512] = (bf16_t)((v2 - mu) * rstd * w[t + 512] + b[t + 512]);
}

// ---------------- fused QKV GEMM: A[4096][768] @ W[2304][768]^T -------------
// cols 0..1535 -> QK[token][1536] bf16 (ld 1536); cols 1536..2303 -> VT[col-1536][4096]
__global__ __launch_bounds__(256, 3) void gemm_qkv_kernel(const bf16_t* __restrict__ A,
                                                          const bf16_t* __restrict__ W,
                                                          bf16_t* __restrict__ outQK,
                                                          bf16_t* __restrict__ outVT) {
    __shared__ bf16_t Alds[128 * 64];
    __shared__ bf16_t Blds[128 * 64];
    const int K = 768;
    const int tid = threadIdx.x;
    const int bm = blockIdx.y, bn = blockIdx.x;
    const int lane = tid & 63, wid = tid >> 6;
    const int wm = wid >> 1, wn = wid & 1;
    const int l15 = lane & 15, lh = lane >> 4;
    f32x4 acc[4][4] = {};

    const int sr = tid >> 1;
    const int scb = (tid & 1) * 4;
    const bf16_t* gA = A + (size_t)(bm * 128 + sr) * K;
    const bf16_t* gB = W + (size_t)(bn * 128 + sr) * K;

    for (int k0 = 0; k0 < K; k0 += 64) {
        __syncthreads();
#pragma unroll
        for (int q = 0; q < 4; ++q) {
            int c = scb + q;
            uint4 da = *(const uint4*)(gA + k0 + c * 8);
            uint4 db = *(const uint4*)(gB + k0 + c * 8);
            int s = c ^ (sr & 7);
            *(uint4*)&Alds[sr * 64 + s * 8] = da;
            *(uint4*)&Blds[sr * 64 + s * 8] = db;
        }
        __syncthreads();
#pragma unroll
        for (int kk = 0; kk < 2; ++kk) {
            bf16x8 av[4], bv[4];
#pragma unroll
            for (int i = 0; i < 4; ++i) {
                int rA = wm * 64 + i * 16 + l15;
                int cc = kk * 4 + lh;
                av[i] = *(const bf16x8*)&Alds[rA * 64 + ((cc ^ (rA & 7)) * 8)];
                int rB = wn * 64 + i * 16 + l15;
                bv[i] = *(const bf16x8*)&Blds[rB * 64 + ((cc ^ (rB & 7)) * 8)];
            }
#pragma unroll
            for (int i = 0; i < 4; ++i)
#pragma unroll
                for (int j = 0; j < 4; ++j)
                    acc[i][j] = __builtin_amdgcn_mfma_f32_16x16x32_bf16(av[i], bv[j], acc[i][j], 0, 0, 0);
        }
    }
#pragma unroll
    for (int i = 0; i < 4; ++i) {
        int row0 = bm * 128 + wm * 64 + i * 16 + lh * 4;
#pragma unroll
        for (int j = 0; j < 4; ++j) {
            int col = bn * 128 + wn * 64 + j * 16 + l15;
            if (col < 1536) {  // uniform per bn-block (1536 % 128 == 0)
#pragma unroll
                for (int p = 0; p < 4; ++p)
                    outQK[(size_t)(row0 + p) * 1536 + col] = (bf16_t)acc[i][j][p];
            } else {
                bf16x4 pk;
#pragma unroll
                for (int p = 0; p < 4; ++p) pk[p] = (bf16_t)acc[i][j][p];
                *(bf16x4*)&outVT[(size_t)(col - 1536) * NTOK + row0] = pk;
            }
        }
    }
}

// ---------------- mlp1 GEMM + GELU: A[4096][768] @ W[3072][768]^T -> bf16 ---
__global__ __launch_bounds__(256, 3) void gemm_gelu_kernel(const bf16_t* __restrict__ A,
                                                           const bf16_t* __restrict__ W,
                                                           const float* __restrict__ bias,
                                                           bf16_t* __restrict__ outB) {
    __shared__ bf16_t Alds[128 * 64];
    __shared__ bf16_t Blds[128 * 64];
    const int K = 768, N = 3072;
    const int tid = threadIdx.x;
    const int bm = blockIdx.y, bn = blockIdx.x;
    const int lane = tid & 63, wid = tid >> 6;
    const int wm = wid >> 1, wn = wid & 1;
    const int l15 = lane & 15, lh = lane >> 4;
    f32x4 acc[4][4] = {};

    const int sr = tid >> 1;
    const int scb = (tid & 1) * 4;
    const bf16_t* gA = A + (size_t)(bm * 128 + sr) * K;
    const bf16_t* gB = W + (size_t)(bn * 128 + sr) * K;

    for (int k0 = 0; k0 < K; k0 += 64) {
        __syncthreads();
#pragma unroll
        for (int q = 0; q < 4; ++q) {
            int c = scb + q;
            uint4 da = *(const uint4*)(gA + k0 + c * 8);
            uint4 db = *(const uint4*)(gB + k0 + c * 8);
            int s = c ^ (sr & 7);
            *(uint4*)&Alds[sr * 64 + s * 8] = da;
            *(uint4*)&Blds[sr * 64 + s * 8] = db;
        }
        __syncthreads();
#pragma unroll
        for (int kk = 0; kk < 2; ++kk) {
            bf16x8 av[4], bv[4];
#pragma unroll
            for (int i = 0; i < 4; ++i) {
                int rA = wm * 64 + i * 16 + l15;
                int cc = kk * 4 + lh;
                av[i] = *(const bf16x8*)&Alds[rA * 64 + ((cc ^ (rA & 7)) * 8)];
                int rB = wn * 64 + i * 16 + l15;
                bv[i] = *(const bf16x8*)&Blds[rB * 64 + ((cc ^ (rB & 7)) * 8)];
            }
#pragma unroll
            for (int i = 0; i < 4; ++i)
#pragma unroll
                for (int j = 0; j < 4; ++j)
                    acc[i][j] = __builtin_amdgcn_mfma_f32_16x16x32_bf16(av[i], bv[j], acc[i][j], 0, 0, 0);
        }
    }
#pragma unroll
    for (int i = 0; i < 4; ++i) {
        int row0 = bm * 128 + wm * 64 + i * 16 + lh * 4;
#pragma unroll
        for (int j = 0; j < 4; ++j) {
            int col = bn * 128 + wn * 64 + j * 16 + l15;
            float bv_ = bias[col];
#pragma unroll
            for (int p = 0; p < 4; ++p) {
                float v = acc[i][j][p] + bv_;
                v = 0.5f * v * (1.f + erff(v * 0.70710678118654752f));
                outB[(size_t)(row0 + p) * N + col] = (bf16_t)v;
            }
        }
    }
}

// ---------------- BN=64 GEMM: C[4096][768] = A[4096][K] @ W[768][K]^T + bias + res
// BM=128, BN=64, 4 waves of 32x64. Used for proj (K=768) and mlp2 (K=3072).
__global__ __launch_bounds__(256, 4) void gemm64_kernel(const bf16_t* __restrict__ A,
                                                        const bf16_t* __restrict__ W,
                                                        const float* __restrict__ bias,
                                                        const float* __restrict__ res,
                                                        float* __restrict__ outF,
                                                        int K) {
    __shared__ bf16_t Alds[128 * 64];
    __shared__ bf16_t Blds[64 * 64];
    const int N = 768;
    const int tid = threadIdx.x;
    const int bm = blockIdx.y, bn = blockIdx.x;
    const int lane = tid & 63, wid = tid >> 6;  // wave owns rows wid*32..+31, all 64 cols
    const int l15 = lane & 15, lh = lane >> 4;
    f32x4 acc[2][4] = {};

    const int sra = tid >> 1;        // A: 128 rows x 8 chunks; 4 chunks/thread
    const int scba = (tid & 1) * 4;
    const bf16_t* gA = A + (size_t)(bm * 128 + sra) * K;
    const int srb = tid >> 2;        // B: 64 rows x 8 chunks; 2 chunks/thread
    const int scbb = (tid & 3) * 2;
    const bf16_t* gB = W + (size_t)(bn * 64 + srb) * K;

    for (int k0 = 0; k0 < K; k0 += 64) {
        __syncthreads();
#pragma unroll
        for (int q = 0; q < 4; ++q) {
            int c = scba + q;
            uint4 da = *(const uint4*)(gA + k0 + c * 8);
            *(uint4*)&Alds[sra * 64 + ((c ^ (sra & 7)) * 8)] = da;
        }
#pragma unroll
        for (int q = 0; q < 2; ++q) {
            int c = scbb + q;
            uint4 db = *(const uint4*)(gB + k0 + c * 8);
            *(uint4*)&Blds[srb * 64 + ((c ^ (srb & 7)) * 8)] = db;
        }
        __syncthreads();
#pragma unroll
        for (int kk = 0; kk < 2; ++kk) {
            bf16x8 av[2], bv[4];
#pragma unroll
            for (int i = 0; i < 2; ++i) {
                int rA = wid * 32 + i * 16 + l15;
                int cc = kk * 4 + lh;
                av[i] = *(const bf16x8*)&Alds[rA * 64 + ((cc ^ (rA & 7)) * 8)];
            }
#pragma unroll
            for (int j = 0; j < 4; ++j) {
                int rB = j * 16 + l15;
                int cc = kk * 4 + lh;
                bv[j] = *(const bf16x8*)&Blds[rB * 64 + ((cc ^ (rB & 7)) * 8)];
            }
#pragma unroll
            for (int i = 0; i < 2; ++i)
#pragma unroll
                for (int j = 0; j < 4; ++j)
                    acc[i][j] = __builtin_amdgcn_mfma_f32_16x16x32_bf16(av[i], bv[j], acc[i][j], 0, 0, 0);
        }
    }
#pragma unroll
    for (int i = 0; i < 2; ++i) {
        int row0 = bm * 128 + wid * 32 + i * 16 + lh * 4;
#pragma unroll
        for (int j = 0; j < 4; ++j) {
            int col = bn * 64 + j * 16 + l15;
            float bv_ = bias[col];
#pragma unroll
            for (int p = 0; p < 4; ++p) {
                size_t idx = (size_t)(row0 + p) * N + col;
                outF[idx] = acc[i][j][p] + bv_ + res[idx];
            }
        }
    }
}

// ---------------- MFMA flash attention (bf16 in, bf16 out) ----------------
__global__ __launch_bounds__(256, 3) void attn_mfma_kernel(const bf16_t* __restrict__ Qp,
                                                           const bf16_t* __restrict__ Kp,
                                                           const bf16_t* __restrict__ VTp,
                                                           bf16_t* __restrict__ Op,
                                                           int ldQ, int ldK,
                                                           int hsQ, int hsK,
                                                           float scale) {
    __shared__ bf16_t Kl[64 * 64];
    __shared__ bf16_t Vl[64 * 64];
    __shared__ bf16_t Pl[4][16 * 64];
    const int tid = threadIdx.x, lane = tid & 63, w = tid >> 6;
    const int l15 = lane & 15, lh = lane >> 4;
    const int q0 = blockIdx.x * 64;
    const int bh = blockIdx.y, b = bh / 12, h = bh % 12;

    const bf16_t* qptr = Qp + (size_t)(b * 1024 + q0 + w * 16 + l15) * ldQ + h * hsQ + lh * 8;
    bf16x8 qf0 = *(const bf16x8*)qptr;
    bf16x8 qf1 = *(const bf16x8*)(qptr + 32);

    f32x4 oacc[4] = {};
    float m_run[4], l_run[4];
#pragma unroll
    for (int p = 0; p < 4; ++p) { m_run[p] = -1e30f; l_run[p] = 0.f; }

    const int srow = tid >> 2;
    const int sc0 = (tid & 3) * 2;
    const bf16_t* kbase = Kp + (size_t)(b * 1024) * ldK + h * hsK;
    const bf16_t* vbase = VTp + (size_t)(h * 64 + srow) * NTOK + b * 1024;

    for (int kt = 0; kt < 1024; kt += 64) {
        __syncthreads();
        const bf16_t* krow = kbase + (size_t)(kt + srow) * ldK;
#pragma unroll
        for (int cc = 0; cc < 2; ++cc) {
            int c = sc0 + cc;
            int sw = (c ^ (srow & 7)) * 8;
            *(uint4*)&Kl[srow * 64 + sw] = *(const uint4*)(krow + c * 8);
            *(uint4*)&Vl[srow * 64 + sw] = *(const uint4*)(vbase + kt + c * 8);
        }
        __syncthreads();

        f32x4 s[4] = {};
#pragma unroll
        for (int t = 0; t < 4; ++t) {
            int key = t * 16 + l15;
            bf16x8 kf0 = *(const bf16x8*)&Kl[key * 64 + ((lh ^ (key & 7)) * 8)];
            bf16x8 kf1 = *(const bf16x8*)&Kl[key * 64 + (((4 + lh) ^ (key & 7)) * 8)];
            s[t] = __builtin_amdgcn_mfma_f32_16x16x32_bf16(qf0, kf0, s[t], 0, 0, 0);
            s[t] = __builtin_amdgcn_mfma_f32_16x16x32_bf16(qf1, kf1, s[t], 0, 0, 0);
        }

#pragma unroll
        for (int p = 0; p < 4; ++p) {
            float v0 = s[0][p] * scale, v1 = s[1][p] * scale;
            float v2 = s[2][p] * scale, v3 = s[3][p] * scale;
            float mloc = fmaxf(fmaxf(v0, v1), fmaxf(v2, v3));
#pragma unroll
            for (int off = 1; off < 16; off <<= 1) mloc = fmaxf(mloc, __shfl_xor(mloc, off));
            float mnew = fmaxf(m_run[p], mloc);
            float corr = __expf(m_run[p] - mnew);
            float p0 = __expf(v0 - mnew), p1 = __expf(v1 - mnew);
            float p2 = __expf(v2 - mnew), p3 = __expf(v3 - mnew);
            float ps = p0 + p1 + p2 + p3;
#pragma unroll
            for (int off = 1; off < 16; off <<= 1) ps += __shfl_xor(ps, off);
            l_run[p] = l_run[p] * corr + ps;
            m_run[p] = mnew;
            oacc[0][p] *= corr; oacc[1][p] *= corr; oacc[2][p] *= corr; oacc[3][p] *= corr;
            int r = lh * 4 + p;
            bf16_t* pr = &Pl[w][r * 64];
            int cb = l15 >> 3, ce = l15 & 7, rs = r & 7;
            pr[((0 + cb) ^ rs) * 8 + ce] = (bf16_t)p0;
            pr[((2 + cb) ^ rs) * 8 + ce] = (bf16_t)p1;
            pr[((4 + cb) ^ rs) * 8 + ce] = (bf16_t)p2;
            pr[((6 + cb) ^ rs) * 8 + ce] = (bf16_t)p3;
        }

#pragma unroll
        for (int kk = 0; kk < 2; ++kk) {
            bf16x8 pf = *(const bf16x8*)&Pl[w][l15 * 64 + (((kk * 4 + lh) ^ (l15 & 7)) * 8)];
#pragma unroll
            for (int dt = 0; dt < 4; ++dt) {
                int d = dt * 16 + l15;
                bf16x8 vf = *(const bf16x8*)&Vl[d * 64 + (((kk * 4 + lh) ^ (d & 7)) * 8)];
                oacc[dt] = __builtin_amdgcn_mfma_f32_16x16x32_bf16(pf, vf, oacc[dt], 0, 0, 0);
            }
        }
    }

    float inv[4];
#pragma unroll
    for (int p = 0; p < 4; ++p) inv[p] = 1.f / l_run[p];
#pragma unroll
    for (int dt = 0; dt < 4; ++dt) {
#pragma unroll
        for (int p = 0; p < 4; ++p) {
            int row = q0 + w * 16 + lh * 4 + p;
            int col = h * 64 + dt * 16 + l15;
            Op[(size_t)(b * 1024 + row) * 768 + col] = (bf16_t)(oacc[dt][p] * inv[p]);
        }
    }
}

// ------------------------------------------------------------------
extern "C" void kernel_launch(void* const* d_in, const int* in_sizes, int n_in,
                              void* d_out, int out_size, void* d_ws, size_t ws_size,
                              hipStream_t stream) {
    const float* x_in   = (const float*)d_in[0];
    const float* src_in = (const float*)d_in[1];
    const float* b_proj   = (const float*)d_in[4];
    const float* b_proj_s = (const float*)d_in[7];
    const float* b_cp     = (const float*)d_in[13];
    const float* b_cp_s   = (const float*)d_in[15];
    const float* mlp1_b   = (const float*)d_in[17];
    const float* mlp2_b   = (const float*)d_in[19];
    const float* mlp1s_b  = (const float*)d_in[21];
    const float* mlp2s_b  = (const float*)d_in[23];
    const float* ln1_w  = (const float*)d_in[24];
    const float* ln1_b  = (const float*)d_in[25];
    const float* ln1s_w = (const float*)d_in[26];
    const float* ln1s_b = (const float*)d_in[27];
    const float* lnc_w  = (const float*)d_in[28];
    const float* lnc_b  = (const float*)d_in[29];
    const float* lncs_w = (const float*)d_in[30];
    const float* lncs_b = (const float*)d_in[31];
    const float* ln2_w  = (const float*)d_in[32];
    const float* ln2_b  = (const float*)d_in[33];
    const float* ln2s_w = (const float*)d_in[34];
    const float* ln2s_b = (const float*)d_in[35];

    char* ws = (char*)d_ws;
    size_t off = 0;
    auto alloc = [&](size_t bytes) -> void* {
        void* p = ws + off;
        off = (off + bytes + 255) & ~(size_t)255;
        return p;
    };

    // bf16 weight buffers
    bf16_t* bw_qkv_x = (bf16_t*)alloc((size_t)2304 * 768 * 2);
    bf16_t* bw_proj_x = (bf16_t*)alloc((size_t)768 * 768 * 2);
    bf16_t* bw_qkv_s = (bf16_t*)alloc((size_t)2304 * 768 * 2);
    bf16_t* bw_proj_s = (bf16_t*)alloc((size_t)768 * 768 * 2);
    bf16_t* bw_cx    = (bf16_t*)alloc((size_t)2304 * 768 * 2);  // [w_qk; w_v]
    bf16_t* bw_cs    = (bf16_t*)alloc((size_t)2304 * 768 * 2);  // [w_qk_src; w_v_src]
    bf16_t* bw_cp    = (bf16_t*)alloc((size_t)768 * 768 * 2);
    bf16_t* bw_cp_s  = (bf16_t*)alloc((size_t)768 * 768 * 2);
    bf16_t* bw_mlp1  = (bf16_t*)alloc((size_t)3072 * 768 * 2);
    bf16_t* bw_mlp2  = (bf16_t*)alloc((size_t)768 * 3072 * 2);
    bf16_t* bw_mlp1s = (bf16_t*)alloc((size_t)3072 * 768 * 2);
    bf16_t* bw_mlp2s = (bf16_t*)alloc((size_t)768 * 3072 * 2);

    bf16_t* arena = (bf16_t*)alloc((size_t)NTOK * 3072 * 2 * 2);  // 2x [4096][3072] bf16
    bf16_t* LN_A = (bf16_t*)alloc((size_t)NTOK * 768 * 2);
    bf16_t* LN_B = (bf16_t*)alloc((size_t)NTOK * 768 * 2);
    bf16_t* O_A  = (bf16_t*)alloc((size_t)NTOK * 768 * 2);
    bf16_t* O_B  = (bf16_t*)alloc((size_t)NTOK * 768 * 2);

    float* Xst = (float*)d_out;                       // x residual state == output 0
    float* Sst = (float*)d_out + (size_t)NTOK * 768;  // src residual state == output 1

    // phase overlays on arena
    bf16_t* SQK = arena;                               // self: [4096][1536]
    bf16_t* VTs = arena + (size_t)NTOK * 1536;         // self: [768][4096]
    bf16_t* QKx = arena;                               // cross: [4096][1536]
    bf16_t* QKs = arena + (size_t)NTOK * 1536;
    bf16_t* VxT = arena + (size_t)NTOK * 3072;         // cross: [768][4096]
    bf16_t* VsT = arena + (size_t)NTOK * 3072 + (size_t)768 * NTOK;
    bf16_t* H_A = arena;                               // mlp: [4096][3072]
    bf16_t* H_B = arena + (size_t)NTOK * 3072;

    // one mega-cvt launch (14 segments; concat cross qk+v into fused buffers)
    CvtTab tab;
    const float* csrc[14] = {(const float*)d_in[2], (const float*)d_in[3],
                             (const float*)d_in[5], (const float*)d_in[6],
                             (const float*)d_in[8], (const float*)d_in[10],
                             (const float*)d_in[9], (const float*)d_in[11],
                             (const float*)d_in[12], (const float*)d_in[14],
                             (const float*)d_in[16], (const float*)d_in[18],
                             (const float*)d_in[20], (const float*)d_in[22]};
    bf16_t* cdst[14] = {bw_qkv_x, bw_proj_x, bw_qkv_s, bw_proj_s,
                        bw_cx, bw_cx + (size_t)1536 * 768,
                        bw_cs, bw_cs + (size_t)1536 * 768,
                        bw_cp, bw_cp_s, bw_mlp1, bw_mlp2, bw_mlp1s, bw_mlp2s};
    int cn[14] = {2304 * 768, 768 * 768, 2304 * 768, 768 * 768,
                  1536 * 768, 768 * 768, 1536 * 768, 768 * 768,
                  768 * 768, 768 * 768, 3072 * 768, 768 * 3072, 3072 * 768, 768 * 3072};
    for (int i = 0; i < 14; ++i) { tab.src[i] = csrc[i]; tab.dst[i] = cdst[i]; tab.n[i] = cn[i]; }
    cvt_all_kernel<<<dim3(1152, 14), 256, 0, stream>>>(tab);

    const dim3 blk(256);
    const dim3 qkv_grid(18, 32);     // N=2304
    const dim3 g64_grid(12, 32);     // N=768, BN=64
    const dim3 gelu_grid(24, 32);    // N=3072
    const dim3 attn_grid(16, 48);

    // ---- x self-attention ----
    ln_kernel<<<NTOK, blk, 0, stream>>>(x_in, ln1_w, ln1_b, LN_A);
    gemm_qkv_kernel<<<qkv_grid, blk, 0, stream>>>(LN_A, bw_qkv_x, SQK, VTs);
    attn_mfma_kernel<<<attn_grid, blk, 0, stream>>>(SQK, SQK + 768, VTs, O_A, 1536, 1536, 64, 64, SCALE_ATTN);
    gemm64_kernel<<<g64_grid, blk, 0, stream>>>(O_A, bw_proj_x, b_proj, x_in, Xst, 768);

    // ---- src self-attention ----
    ln_kernel<<<NTOK, blk, 0, stream>>>(src_in, ln1s_w, ln1s_b, LN_A);
    gemm_qkv_kernel<<<qkv_grid, blk, 0, stream>>>(LN_A, bw_qkv_s, SQK, VTs);
    attn_mfma_kernel<<<attn_grid, blk, 0, stream>>>(SQK, SQK + 768, VTs, O_A, 1536, 1536, 64, 64, SCALE_ATTN);
    gemm64_kernel<<<g64_grid, blk, 0, stream>>>(O_A, bw_proj_s, b_proj_s, src_in, Sst, 768);

    // ---- cross attention ----
    ln_kernel<<<NTOK, blk, 0, stream>>>(Xst, lnc_w, lnc_b, LN_A);
    ln_kernel<<<NTOK, blk, 0, stream>>>(Sst, lncs_w, lncs_b, LN_B);
    gemm_qkv_kernel<<<qkv_grid, blk, 0, stream>>>(LN_A, bw_cx, QKx, VxT);
    gemm_qkv_kernel<<<qkv_grid, blk, 0, stream>>>(LN_B, bw_cs, QKs, VsT);
    // y   = softmax(q · q_s) @ v_s
    attn_mfma_kernel<<<attn_grid, blk, 0, stream>>>(QKx, QKs, VsT, O_A, 1536, 1536, 128, 128, SCALE_ATTN);
    // y_s = softmax(k_s · kx) @ v
    attn_mfma_kernel<<<attn_grid, blk, 0, stream>>>(QKs + 64, QKx + 64, VxT, O_B, 1536, 1536, 128, 128, SCALE_ATTN);
    gemm64_kernel<<<g64_grid, blk, 0, stream>>>(O_A, bw_cp, b_cp, Xst, Xst, 768);
    gemm64_kernel<<<g64_grid, blk, 0, stream>>>(O_B, bw_cp_s, b_cp_s, Sst, Sst, 768);

    // ---- MLPs ----
    ln_kernel<<<NTOK, blk, 0, stream>>>(Xst, ln2_w, ln2_b, LN_A);
    ln_kernel<<<NTOK, blk, 0, stream>>>(Sst, ln2s_w, ln2s_b, LN_B);
    gemm_gelu_kernel<<<gelu_grid, blk, 0, stream>>>(LN_A, bw_mlp1, mlp1_b, H_A);
    gemm_gelu_kernel<<<gelu_grid, blk, 0, stream>>>(LN_B, bw_mlp1s, mlp1s_b, H_B);
    gemm64_kernel<<<g64_grid, blk, 0, stream>>>(H_A, bw_mlp2, mlp2_b, Xst, Xst, 3072);
    gemm64_kernel<<<g64_grid, blk, 0, stream>>>(H_B, bw_mlp2s, mlp2s_b, Sst, Sst, 3072);
}

// Round 6
// 789.308 us; speedup vs baseline: 2.7609x; 1.0102x over previous
//
#include <hip/hip_runtime.h>
#include <hip/hip_bf16.h>
#include <cmath>

// CrossAttentionTransformerBlock: B=4, N=M=1024, C=768, H=12, HD=64, HID=3072
// Round 5->6: global_load_lds staging everywhere (pre-swizzled source, linear LDS
// dest, swizzled read), attention QBLK=128 (2x MFMA density, half K/V traffic),
// bijective XCD-chunk remaps for L2 locality (attn: per-XCD bh ownership;
// GEMM: per-XCD bm rows).

typedef __bf16 bf16_t;
typedef __attribute__((ext_vector_type(8))) __bf16 bf16x8;
typedef __attribute__((ext_vector_type(4))) __bf16 bf16x4;
typedef __attribute__((ext_vector_type(4))) float f32x4;

#define NTOK 4096          // B*N rows
#define SCALE_ATTN 0.125f  // HD^-0.5

// global -> LDS direct DMA, 16B/lane. LDS dest must be wave-uniform;
// per-lane global src carries the swizzle (guide §5 caveat, m104/m173).
__device__ __forceinline__ void gload16(const void* g, void* l) {
    __builtin_amdgcn_global_load_lds((const __attribute__((address_space(1))) void*)g,
                                     (__attribute__((address_space(3))) void*)l, 16, 0, 0);
}

// ---------------- mega f32->bf16 conversion (14 segments, one launch) -------
struct CvtTab {
    const float* src[14];
    bf16_t* dst[14];
    int n[14];
};
__global__ __launch_bounds__(256) void cvt_all_kernel(CvtTab t) {
    int seg = blockIdx.y;
    int base = blockIdx.x * 2048 + threadIdx.x * 8;
    if (base >= t.n[seg]) return;
    const float* s = t.src[seg];
    float4 a = *(const float4*)(s + base);
    float4 b = *(const float4*)(s + base + 4);
    bf16x8 o;
    o[0] = (bf16_t)a.x; o[1] = (bf16_t)a.y; o[2] = (bf16_t)a.z; o[3] = (bf16_t)a.w;
    o[4] = (bf16_t)b.x; o[5] = (bf16_t)b.y; o[6] = (bf16_t)b.z; o[7] = (bf16_t)b.w;
    *(bf16x8*)(t.dst[seg] + base) = o;
}

// ---------------- LayerNorm over C=768, f32 in -> bf16 out ----------------
__global__ __launch_bounds__(256) void ln_kernel(const float* __restrict__ X,
                                                 const float* __restrict__ w,
                                                 const float* __restrict__ b,
                                                 bf16_t* __restrict__ out) {
    int row = blockIdx.x, t = threadIdx.x;
    const float* x = X + (size_t)row * 768;
    float v0 = x[t], v1 = x[t + 256], v2 = x[t + 512];
    float s = v0 + v1 + v2;
    float s2 = v0 * v0 + v1 * v1 + v2 * v2;
#pragma unroll
    for (int off = 32; off > 0; off >>= 1) {
        s += __shfl_down(s, off);
        s2 += __shfl_down(s2, off);
    }
    __shared__ float as_[4], as2_[4];
    int wave = t >> 6;
    if ((t & 63) == 0) { as_[wave] = s; as2_[wave] = s2; }
    __syncthreads();
    float tot = as_[0] + as_[1] + as_[2] + as_[3];
    float tot2 = as2_[0] + as2_[1] + as2_[2] + as2_[3];
    float mu = tot * (1.f / 768.f);
    float var = tot2 * (1.f / 768.f) - mu * mu;
    float rstd = rsqrtf(var + 1e-6f);
    bf16_t* o = out + (size_t)row * 768;
    o[t]       = (bf16_t)((v0 - mu) * rstd * w[t]       + b[t]);
    o[t + 256] = (bf16_t)((v1 - mu) * rstd * w[t + 256] + b[t + 256]);
    o[t + 512] = (bf16_t)((v2 - mu) * rstd * w[t + 512] + b[t + 512]);
}

// ---------------- fused QKV GEMM: A[4096][768] @ W[2304][768]^T -------------
// cols 0..1535 -> QK[token][1536]; cols 1536..2303 -> VT[col-1536][4096]
__global__ __launch_bounds__(256, 3) void gemm_qkv_kernel(const bf16_t* __restrict__ A,
                                                          const bf16_t* __restrict__ W,
                                                          bf16_t* __restrict__ outQK,
                                                          bf16_t* __restrict__ outVT) {
    __shared__ bf16_t Alds[128 * 64];
    __shared__ bf16_t Blds[128 * 64];
    const int K = 768, GX = 18;
    const int tid = threadIdx.x;
    // chunked XCD remap: xcd owns bm in [xcd*4, xcd*4+4), all bn
    const int f = blockIdx.x + GX * blockIdx.y;
    const int slot = f >> 3;
    const int bm = (f & 7) * 4 + slot / GX, bn = slot % GX;
    const int lane = tid & 63, wid = tid >> 6;
    const int wm = wid >> 1, wn = wid & 1;
    const int l15 = lane & 15, lh = lane >> 4;
    f32x4 acc[4][4] = {};

    const int lr = lane >> 3;              // row within 8-row segment
    const int lc = ((lane & 7) ^ lr) * 8;  // pre-swizzled source chunk (elements)
    const bf16_t* gA = A + (size_t)(bm * 128 + lr) * K + lc;
    const bf16_t* gB = W + (size_t)(bn * 128 + lr) * K + lc;

    for (int k0 = 0; k0 < K; k0 += 64) {
        __syncthreads();
#pragma unroll
        for (int q = 0; q < 4; ++q) {
            int r0 = (wid * 4 + q) * 8;
            gload16(gA + (size_t)r0 * K + k0, &Alds[r0 * 64]);
            gload16(gB + (size_t)r0 * K + k0, &Blds[r0 * 64]);
        }
        __syncthreads();
#pragma unroll
        for (int kk = 0; kk < 2; ++kk) {
            bf16x8 av[4], bv[4];
#pragma unroll
            for (int i = 0; i < 4; ++i) {
                int rA = wm * 64 + i * 16 + l15;
                int cc = kk * 4 + lh;
                av[i] = *(const bf16x8*)&Alds[rA * 64 + ((cc ^ (rA & 7)) * 8)];
                int rB = wn * 64 + i * 16 + l15;
                bv[i] = *(const bf16x8*)&Blds[rB * 64 + ((cc ^ (rB & 7)) * 8)];
            }
#pragma unroll
            for (int i = 0; i < 4; ++i)
#pragma unroll
                for (int j = 0; j < 4; ++j)
                    acc[i][j] = __builtin_amdgcn_mfma_f32_16x16x32_bf16(av[i], bv[j], acc[i][j], 0, 0, 0);
        }
    }
#pragma unroll
    for (int i = 0; i < 4; ++i) {
        int row0 = bm * 128 + wm * 64 + i * 16 + lh * 4;
#pragma unroll
        for (int j = 0; j < 4; ++j) {
            int col = bn * 128 + wn * 64 + j * 16 + l15;
            if (col < 1536) {  // uniform per bn-block (1536 % 128 == 0)
#pragma unroll
                for (int p = 0; p < 4; ++p)
                    outQK[(size_t)(row0 + p) * 1536 + col] = (bf16_t)acc[i][j][p];
            } else {
                bf16x4 pk;
#pragma unroll
                for (int p = 0; p < 4; ++p) pk[p] = (bf16_t)acc[i][j][p];
                *(bf16x4*)&outVT[(size_t)(col - 1536) * NTOK + row0] = pk;
            }
        }
    }
}

// ---------------- mlp1 GEMM + GELU: A[4096][768] @ W[3072][768]^T -> bf16 ---
__global__ __launch_bounds__(256, 3) void gemm_gelu_kernel(const bf16_t* __restrict__ A,
                                                           const bf16_t* __restrict__ W,
                                                           const float* __restrict__ bias,
                                                           bf16_t* __restrict__ outB) {
    __shared__ bf16_t Alds[128 * 64];
    __shared__ bf16_t Blds[128 * 64];
    const int K = 768, N = 3072, GX = 24;
    const int tid = threadIdx.x;
    const int f = blockIdx.x + GX * blockIdx.y;
    const int slot = f >> 3;
    const int bm = (f & 7) * 4 + slot / GX, bn = slot % GX;
    const int lane = tid & 63, wid = tid >> 6;
    const int wm = wid >> 1, wn = wid & 1;
    const int l15 = lane & 15, lh = lane >> 4;
    f32x4 acc[4][4] = {};

    const int lr = lane >> 3;
    const int lc = ((lane & 7) ^ lr) * 8;
    const bf16_t* gA = A + (size_t)(bm * 128 + lr) * K + lc;
    const bf16_t* gB = W + (size_t)(bn * 128 + lr) * K + lc;

    for (int k0 = 0; k0 < K; k0 += 64) {
        __syncthreads();
#pragma unroll
        for (int q = 0; q < 4; ++q) {
            int r0 = (wid * 4 + q) * 8;
            gload16(gA + (size_t)r0 * K + k0, &Alds[r0 * 64]);
            gload16(gB + (size_t)r0 * K + k0, &Blds[r0 * 64]);
        }
        __syncthreads();
#pragma unroll
        for (int kk = 0; kk < 2; ++kk) {
            bf16x8 av[4], bv[4];
#pragma unroll
            for (int i = 0; i < 4; ++i) {
                int rA = wm * 64 + i * 16 + l15;
                int cc = kk * 4 + lh;
                av[i] = *(const bf16x8*)&Alds[rA * 64 + ((cc ^ (rA & 7)) * 8)];
                int rB = wn * 64 + i * 16 + l15;
                bv[i] = *(const bf16x8*)&Blds[rB * 64 + ((cc ^ (rB & 7)) * 8)];
            }
#pragma unroll
            for (int i = 0; i < 4; ++i)
#pragma unroll
                for (int j = 0; j < 4; ++j)
                    acc[i][j] = __builtin_amdgcn_mfma_f32_16x16x32_bf16(av[i], bv[j], acc[i][j], 0, 0, 0);
        }
    }
#pragma unroll
    for (int i = 0; i < 4; ++i) {
        int row0 = bm * 128 + wm * 64 + i * 16 + lh * 4;
#pragma unroll
        for (int j = 0; j < 4; ++j) {
            int col = bn * 128 + wn * 64 + j * 16 + l15;
            float bv_ = bias[col];
#pragma unroll
            for (int p = 0; p < 4; ++p) {
                float v = acc[i][j][p] + bv_;
                v = 0.5f * v * (1.f + erff(v * 0.70710678118654752f));
                outB[(size_t)(row0 + p) * N + col] = (bf16_t)v;
            }
        }
    }
}

// ---------------- BN=64 GEMM: C[4096][768] = A[4096][K] @ W[768][K]^T + bias + res
__global__ __launch_bounds__(256, 4) void gemm64_kernel(const bf16_t* __restrict__ A,
                                                        const bf16_t* __restrict__ W,
                                                        const float* __restrict__ bias,
                                                        const float* __restrict__ res,
                                                        float* __restrict__ outF,
                                                        int K) {
    __shared__ bf16_t Alds[128 * 64];
    __shared__ bf16_t Blds[64 * 64];
    const int N = 768, GX = 12;
    const int tid = threadIdx.x;
    const int f = blockIdx.x + GX * blockIdx.y;
    const int slot = f >> 3;
    const int bm = (f & 7) * 4 + slot / GX, bn = slot % GX;
    const int lane = tid & 63, wid = tid >> 6;
    const int l15 = lane & 15, lh = lane >> 4;
    f32x4 acc[2][4] = {};

    const int lr = lane >> 3;
    const int lc = ((lane & 7) ^ lr) * 8;
    const bf16_t* gA = A + (size_t)(bm * 128 + lr) * K + lc;
    const bf16_t* gB = W + (size_t)(bn * 64 + lr) * K + lc;

    for (int k0 = 0; k0 < K; k0 += 64) {
        __syncthreads();
#pragma unroll
        for (int q = 0; q < 4; ++q) {
            int r0 = (wid * 4 + q) * 8;
            gload16(gA + (size_t)r0 * K + k0, &Alds[r0 * 64]);
        }
#pragma unroll
        for (int q = 0; q < 2; ++q) {
            int r0 = (wid * 2 + q) * 8;
            gload16(gB + (size_t)r0 * K + k0, &Blds[r0 * 64]);
        }
        __syncthreads();
#pragma unroll
        for (int kk = 0; kk < 2; ++kk) {
            bf16x8 av[2], bv[4];
#pragma unroll
            for (int i = 0; i < 2; ++i) {
                int rA = wid * 32 + i * 16 + l15;
                int cc = kk * 4 + lh;
                av[i] = *(const bf16x8*)&Alds[rA * 64 + ((cc ^ (rA & 7)) * 8)];
            }
#pragma unroll
            for (int j = 0; j < 4; ++j) {
                int rB = j * 16 + l15;
                int cc = kk * 4 + lh;
                bv[j] = *(const bf16x8*)&Blds[rB * 64 + ((cc ^ (rB & 7)) * 8)];
            }
#pragma unroll
            for (int i = 0; i < 2; ++i)
#pragma unroll
                for (int j = 0; j < 4; ++j)
                    acc[i][j] = __builtin_amdgcn_mfma_f32_16x16x32_bf16(av[i], bv[j], acc[i][j], 0, 0, 0);
        }
    }
#pragma unroll
    for (int i = 0; i < 2; ++i) {
        int row0 = bm * 128 + wid * 32 + i * 16 + lh * 4;
#pragma unroll
        for (int j = 0; j < 4; ++j) {
            int col = bn * 64 + j * 16 + l15;
            float bv_ = bias[col];
#pragma unroll
            for (int p = 0; p < 4; ++p) {
                size_t idx = (size_t)(row0 + p) * N + col;
                outF[idx] = acc[i][j][p] + bv_ + res[idx];
            }
        }
    }
}

// ---------------- MFMA flash attention (bf16 in/out), QBLK=128 --------------
// grid (8, 48). XCD remap: each XCD owns 6 bh pairs (K/V resident in its L2).
__global__ __launch_bounds__(256, 2) void attn_mfma_kernel(const bf16_t* __restrict__ Qp,
                                                           const bf16_t* __restrict__ Kp,
                                                           const bf16_t* __restrict__ VTp,
                                                           bf16_t* __restrict__ Op,
                                                           int ldQ, int ldK,
                                                           int hsQ, int hsK,
                                                           float scale) {
    __shared__ bf16_t Kl[64 * 64];
    __shared__ bf16_t Vl[64 * 64];
    __shared__ bf16_t Pl[4][16 * 64];
    const int tid = threadIdx.x, lane = tid & 63, w = tid >> 6;
    const int l15 = lane & 15, lh = lane >> 4;
    const int f = blockIdx.x + (blockIdx.y << 3);
    const int slot = f >> 3;
    const int bh = (f & 7) * 6 + (slot >> 3);
    const int q0 = (slot & 7) * 128;
    const int b = bh / 12, h = bh % 12;

    // Q fragments for 2 q-groups of 64 rows each
    bf16x8 qf[2][2];
#pragma unroll
    for (int g = 0; g < 2; ++g) {
        const bf16_t* qptr = Qp + (size_t)(b * 1024 + q0 + g * 64 + w * 16 + l15) * ldQ + h * hsQ + lh * 8;
        qf[g][0] = *(const bf16x8*)qptr;
        qf[g][1] = *(const bf16x8*)(qptr + 32);
    }

    f32x4 oacc[2][4] = {};
    float m_run[2][4], l_run[2][4];
#pragma unroll
    for (int g = 0; g < 2; ++g)
#pragma unroll
        for (int p = 0; p < 4; ++p) { m_run[g][p] = -1e30f; l_run[g][p] = 0.f; }

    const int lr = lane >> 3;              // row within 8-row staging segment
    const int lc = ((lane & 7) ^ lr) * 8;  // pre-swizzled source chunk
    const bf16_t* kbase = Kp + (size_t)(b * 1024 + lr) * ldK + h * hsK + lc;
    const bf16_t* vbase = VTp + (size_t)(h * 64 + lr) * NTOK + b * 1024 + lc;

    for (int kt = 0; kt < 1024; kt += 64) {
        __syncthreads();
#pragma unroll
        for (int q = 0; q < 2; ++q) {
            int r0 = (w * 2 + q) * 8;
            gload16(kbase + (size_t)(kt + r0) * ldK, &Kl[r0 * 64]);
            gload16(vbase + (size_t)r0 * NTOK + kt, &Vl[r0 * 64]);
        }
        __syncthreads();

#pragma unroll
        for (int g = 0; g < 2; ++g) {
            // QK^T: 16 q-rows x 64 keys
            f32x4 s[4] = {};
#pragma unroll
            for (int t = 0; t < 4; ++t) {
                int key = t * 16 + l15;
                bf16x8 kf0 = *(const bf16x8*)&Kl[key * 64 + ((lh ^ (key & 7)) * 8)];
                bf16x8 kf1 = *(const bf16x8*)&Kl[key * 64 + (((4 + lh) ^ (key & 7)) * 8)];
                s[t] = __builtin_amdgcn_mfma_f32_16x16x32_bf16(qf[g][0], kf0, s[t], 0, 0, 0);
                s[t] = __builtin_amdgcn_mfma_f32_16x16x32_bf16(qf[g][1], kf1, s[t], 0, 0, 0);
            }
            // online softmax; lane owns rows r = lh*4+p, key col = t*16+l15
#pragma unroll
            for (int p = 0; p < 4; ++p) {
                float v0 = s[0][p] * scale, v1 = s[1][p] * scale;
                float v2 = s[2][p] * scale, v3 = s[3][p] * scale;
                float mloc = fmaxf(fmaxf(v0, v1), fmaxf(v2, v3));
#pragma unroll
                for (int off = 1; off < 16; off <<= 1) mloc = fmaxf(mloc, __shfl_xor(mloc, off));
                float mnew = fmaxf(m_run[g][p], mloc);
                float corr = __expf(m_run[g][p] - mnew);
                float p0 = __expf(v0 - mnew), p1 = __expf(v1 - mnew);
                float p2 = __expf(v2 - mnew), p3 = __expf(v3 - mnew);
                float ps = p0 + p1 + p2 + p3;
#pragma unroll
                for (int off = 1; off < 16; off <<= 1) ps += __shfl_xor(ps, off);
                l_run[g][p] = l_run[g][p] * corr + ps;
                m_run[g][p] = mnew;
                oacc[g][0][p] *= corr; oacc[g][1][p] *= corr;
                oacc[g][2][p] *= corr; oacc[g][3][p] *= corr;
                int r = lh * 4 + p;
                bf16_t* pr = &Pl[w][r * 64];
                int cb = l15 >> 3, ce = l15 & 7, rs = r & 7;
                pr[((0 + cb) ^ rs) * 8 + ce] = (bf16_t)p0;
                pr[((2 + cb) ^ rs) * 8 + ce] = (bf16_t)p1;
                pr[((4 + cb) ^ rs) * 8 + ce] = (bf16_t)p2;
                pr[((6 + cb) ^ rs) * 8 + ce] = (bf16_t)p3;
            }
            // PV: same-wave Pl write->read (in-order LDS; compiler inserts waits)
#pragma unroll
            for (int kk = 0; kk < 2; ++kk) {
                bf16x8 pf = *(const bf16x8*)&Pl[w][l15 * 64 + (((kk * 4 + lh) ^ (l15 & 7)) * 8)];
#pragma unroll
                for (int dt = 0; dt < 4; ++dt) {
                    int d = dt * 16 + l15;
                    bf16x8 vf = *(const bf16x8*)&Vl[d * 64 + (((kk * 4 + lh) ^ (d & 7)) * 8)];
                    oacc[g][dt] = __builtin_amdgcn_mfma_f32_16x16x32_bf16(pf, vf, oacc[g][dt], 0, 0, 0);
                }
            }
        }
    }

#pragma unroll
    for (int g = 0; g < 2; ++g) {
        float inv[4];
#pragma unroll
        for (int p = 0; p < 4; ++p) inv[p] = 1.f / l_run[g][p];
#pragma unroll
        for (int dt = 0; dt < 4; ++dt) {
#pragma unroll
            for (int p = 0; p < 4; ++p) {
                int row = q0 + g * 64 + w * 16 + lh * 4 + p;
                int col = h * 64 + dt * 16 + l15;
                Op[(size_t)(b * 1024 + row) * 768 + col] = (bf16_t)(oacc[g][dt][p] * inv[p]);
            }
        }
    }
}

// ------------------------------------------------------------------
extern "C" void kernel_launch(void* const* d_in, const int* in_sizes, int n_in,
                              void* d_out, int out_size, void* d_ws, size_t ws_size,
                              hipStream_t stream) {
    const float* x_in   = (const float*)d_in[0];
    const float* src_in = (const float*)d_in[1];
    const float* b_proj   = (const float*)d_in[4];
    const float* b_proj_s = (const float*)d_in[7];
    const float* b_cp     = (const float*)d_in[13];
    const float* b_cp_s   = (const float*)d_in[15];
    const float* mlp1_b   = (const float*)d_in[17];
    const float* mlp2_b   = (const float*)d_in[19];
    const float* mlp1s_b  = (const float*)d_in[21];
    const float* mlp2s_b  = (const float*)d_in[23];
    const float* ln1_w  = (const float*)d_in[24];
    const float* ln1_b  = (const float*)d_in[25];
    const float* ln1s_w = (const float*)d_in[26];
    const float* ln1s_b = (const float*)d_in[27];
    const float* lnc_w  = (const float*)d_in[28];
    const float* lnc_b  = (const float*)d_in[29];
    const float* lncs_w = (const float*)d_in[30];
    const float* lncs_b = (const float*)d_in[31];
    const float* ln2_w  = (const float*)d_in[32];
    const float* ln2_b  = (const float*)d_in[33];
    const float* ln2s_w = (const float*)d_in[34];
    const float* ln2s_b = (const float*)d_in[35];

    char* ws = (char*)d_ws;
    size_t off = 0;
    auto alloc = [&](size_t bytes) -> void* {
        void* p = ws + off;
        off = (off + bytes + 255) & ~(size_t)255;
        return p;
    };

    bf16_t* bw_qkv_x = (bf16_t*)alloc((size_t)2304 * 768 * 2);
    bf16_t* bw_proj_x = (bf16_t*)alloc((size_t)768 * 768 * 2);
    bf16_t* bw_qkv_s = (bf16_t*)alloc((size_t)2304 * 768 * 2);
    bf16_t* bw_proj_s = (bf16_t*)alloc((size_t)768 * 768 * 2);
    bf16_t* bw_cx    = (bf16_t*)alloc((size_t)2304 * 768 * 2);  // [w_qk; w_v]
    bf16_t* bw_cs    = (bf16_t*)alloc((size_t)2304 * 768 * 2);  // [w_qk_src; w_v_src]
    bf16_t* bw_cp    = (bf16_t*)alloc((size_t)768 * 768 * 2);
    bf16_t* bw_cp_s  = (bf16_t*)alloc((size_t)768 * 768 * 2);
    bf16_t* bw_mlp1  = (bf16_t*)alloc((size_t)3072 * 768 * 2);
    bf16_t* bw_mlp2  = (bf16_t*)alloc((size_t)768 * 3072 * 2);
    bf16_t* bw_mlp1s = (bf16_t*)alloc((size_t)3072 * 768 * 2);
    bf16_t* bw_mlp2s = (bf16_t*)alloc((size_t)768 * 3072 * 2);

    bf16_t* arena = (bf16_t*)alloc((size_t)NTOK * 3072 * 2 * 2);
    bf16_t* LN_A = (bf16_t*)alloc((size_t)NTOK * 768 * 2);
    bf16_t* LN_B = (bf16_t*)alloc((size_t)NTOK * 768 * 2);
    bf16_t* O_A  = (bf16_t*)alloc((size_t)NTOK * 768 * 2);
    bf16_t* O_B  = (bf16_t*)alloc((size_t)NTOK * 768 * 2);

    float* Xst = (float*)d_out;
    float* Sst = (float*)d_out + (size_t)NTOK * 768;

    bf16_t* SQK = arena;                               // self: [4096][1536]
    bf16_t* VTs = arena + (size_t)NTOK * 1536;         // self: [768][4096]
    bf16_t* QKx = arena;                               // cross: [4096][1536]
    bf16_t* QKs = arena + (size_t)NTOK * 1536;
    bf16_t* VxT = arena + (size_t)NTOK * 3072;         // cross: [768][4096]
    bf16_t* VsT = arena + (size_t)NTOK * 3072 + (size_t)768 * NTOK;
    bf16_t* H_A = arena;                               // mlp: [4096][3072]
    bf16_t* H_B = arena + (size_t)NTOK * 3072;

    CvtTab tab;
    const float* csrc[14] = {(const float*)d_in[2], (const float*)d_in[3],
                             (const float*)d_in[5], (const float*)d_in[6],
                             (const float*)d_in[8], (const float*)d_in[10],
                             (const float*)d_in[9], (const float*)d_in[11],
                             (const float*)d_in[12], (const float*)d_in[14],
                             (const float*)d_in[16], (const float*)d_in[18],
                             (const float*)d_in[20], (const float*)d_in[22]};
    bf16_t* cdst[14] = {bw_qkv_x, bw_proj_x, bw_qkv_s, bw_proj_s,
                        bw_cx, bw_cx + (size_t)1536 * 768,
                        bw_cs, bw_cs + (size_t)1536 * 768,
                        bw_cp, bw_cp_s, bw_mlp1, bw_mlp2, bw_mlp1s, bw_mlp2s};
    int cn[14] = {2304 * 768, 768 * 768, 2304 * 768, 768 * 768,
                  1536 * 768, 768 * 768, 1536 * 768, 768 * 768,
                  768 * 768, 768 * 768, 3072 * 768, 768 * 3072, 3072 * 768, 768 * 3072};
    for (int i = 0; i < 14; ++i) { tab.src[i] = csrc[i]; tab.dst[i] = cdst[i]; tab.n[i] = cn[i]; }
    cvt_all_kernel<<<dim3(1152, 14), 256, 0, stream>>>(tab);

    const dim3 blk(256);
    const dim3 qkv_grid(18, 32);
    const dim3 g64_grid(12, 32);
    const dim3 gelu_grid(24, 32);
    const dim3 attn_grid(8, 48);

    // ---- x self-attention ----
    ln_kernel<<<NTOK, blk, 0, stream>>>(x_in, ln1_w, ln1_b, LN_A);
    gemm_qkv_kernel<<<qkv_grid, blk, 0, stream>>>(LN_A, bw_qkv_x, SQK, VTs);
    attn_mfma_kernel<<<attn_grid, blk, 0, stream>>>(SQK, SQK + 768, VTs, O_A, 1536, 1536, 64, 64, SCALE_ATTN);
    gemm64_kernel<<<g64_grid, blk, 0, stream>>>(O_A, bw_proj_x, b_proj, x_in, Xst, 768);

    // ---- src self-attention ----
    ln_kernel<<<NTOK, blk, 0, stream>>>(src_in, ln1s_w, ln1s_b, LN_A);
    gemm_qkv_kernel<<<qkv_grid, blk, 0, stream>>>(LN_A, bw_qkv_s, SQK, VTs);
    attn_mfma_kernel<<<attn_grid, blk, 0, stream>>>(SQK, SQK + 768, VTs, O_A, 1536, 1536, 64, 64, SCALE_ATTN);
    gemm64_kernel<<<g64_grid, blk, 0, stream>>>(O_A, bw_proj_s, b_proj_s, src_in, Sst, 768);

    // ---- cross attention ----
    ln_kernel<<<NTOK, blk, 0, stream>>>(Xst, lnc_w, lnc_b, LN_A);
    ln_kernel<<<NTOK, blk, 0, stream>>>(Sst, lncs_w, lncs_b, LN_B);
    gemm_qkv_kernel<<<qkv_grid, blk, 0, stream>>>(LN_A, bw_cx, QKx, VxT);
    gemm_qkv_kernel<<<qkv_grid, blk, 0, stream>>>(LN_B, bw_cs, QKs, VsT);
    // y   = softmax(q · q_s) @ v_s
    attn_mfma_kernel<<<attn_grid, blk, 0, stream>>>(QKx, QKs, VsT, O_A, 1536, 1536, 128, 128, SCALE_ATTN);
    // y_s = softmax(k_s · kx) @ v
    attn_mfma_kernel<<<attn_grid, blk, 0, stream>>>(QKs + 64, QKx + 64, VxT, O_B, 1536, 1536, 128, 128, SCALE_ATTN);
    gemm64_kernel<<<g64_grid, blk, 0, stream>>>(O_A, bw_cp, b_cp, Xst, Xst, 768);
    gemm64_kernel<<<g64_grid, blk, 0, stream>>>(O_B, bw_cp_s, b_cp_s, Sst, Sst, 768);

    // ---- MLPs ----
    ln_kernel<<<NTOK, blk, 0, stream>>>(Xst, ln2_w, ln2_b, LN_A);
    ln_kernel<<<NTOK, blk, 0, stream>>>(Sst, ln2s_w, ln2s_b, LN_B);
    gemm_gelu_kernel<<<gelu_grid, blk, 0, stream>>>(LN_A, bw_mlp1, mlp1_b, H_A);
    gemm_gelu_kernel<<<gelu_grid, blk, 0, stream>>>(LN_B, bw_mlp1s, mlp1s_b, H_B);
    gemm64_kernel<<<g64_grid, blk, 0, stream>>>(H_A, bw_mlp2, mlp2_b, Xst, Xst, 3072);
    gemm64_kernel<<<g64_grid, blk, 0, stream>>>(H_B, bw_mlp2s, mlp2s_b, Sst, Sst, 3072);
}

// Round 7
// 676.757 us; speedup vs baseline: 3.2201x; 1.1663x over previous
//
#include <hip/hip_runtime.h>
#include <hip/hip_bf16.h>
#include <cmath>

// CrossAttentionTransformerBlock: B=4, N=M=1024, C=768, H=12, HD=64, HID=3072
// Round 6->7: attention back to QBLK=64 (768 blocks = 3/CU) + double-buffered
// K/V LDS with prefetch-before-compute (one barrier per tile). Keeps
// global_load_lds + XCD bh-remap from round 6. GEMMs unchanged.

typedef __bf16 bf16_t;
typedef __attribute__((ext_vector_type(8))) __bf16 bf16x8;
typedef __attribute__((ext_vector_type(4))) __bf16 bf16x4;
typedef __attribute__((ext_vector_type(4))) float f32x4;

#define NTOK 4096          // B*N rows
#define SCALE_ATTN 0.125f  // HD^-0.5

// global -> LDS direct DMA, 16B/lane. LDS dest must be wave-uniform;
// per-lane global src carries the swizzle (guide §5 caveat, m104/m173).
__device__ __forceinline__ void gload16(const void* g, void* l) {
    __builtin_amdgcn_global_load_lds((const __attribute__((address_space(1))) void*)g,
                                     (__attribute__((address_space(3))) void*)l, 16, 0, 0);
}

// ---------------- mega f32->bf16 conversion (14 segments, one launch) -------
struct CvtTab {
    const float* src[14];
    bf16_t* dst[14];
    int n[14];
};
__global__ __launch_bounds__(256) void cvt_all_kernel(CvtTab t) {
    int seg = blockIdx.y;
    int base = blockIdx.x * 2048 + threadIdx.x * 8;
    if (base >= t.n[seg]) return;
    const float* s = t.src[seg];
    float4 a = *(const float4*)(s + base);
    float4 b = *(const float4*)(s + base + 4);
    bf16x8 o;
    o[0] = (bf16_t)a.x; o[1] = (bf16_t)a.y; o[2] = (bf16_t)a.z; o[3] = (bf16_t)a.w;
    o[4] = (bf16_t)b.x; o[5] = (bf16_t)b.y; o[6] = (bf16_t)b.z; o[7] = (bf16_t)b.w;
    *(bf16x8*)(t.dst[seg] + base) = o;
}

// ---------------- LayerNorm over C=768, f32 in -> bf16 out ----------------
__global__ __launch_bounds__(256) void ln_kernel(const float* __restrict__ X,
                                                 const float* __restrict__ w,
                                                 const float* __restrict__ b,
                                                 bf16_t* __restrict__ out) {
    int row = blockIdx.x, t = threadIdx.x;
    const float* x = X + (size_t)row * 768;
    float v0 = x[t], v1 = x[t + 256], v2 = x[t + 512];
    float s = v0 + v1 + v2;
    float s2 = v0 * v0 + v1 * v1 + v2 * v2;
#pragma unroll
    for (int off = 32; off > 0; off >>= 1) {
        s += __shfl_down(s, off);
        s2 += __shfl_down(s2, off);
    }
    __shared__ float as_[4], as2_[4];
    int wave = t >> 6;
    if ((t & 63) == 0) { as_[wave] = s; as2_[wave] = s2; }
    __syncthreads();
    float tot = as_[0] + as_[1] + as_[2] + as_[3];
    float tot2 = as2_[0] + as2_[1] + as2_[2] + as2_[3];
    float mu = tot * (1.f / 768.f);
    float var = tot2 * (1.f / 768.f) - mu * mu;
    float rstd = rsqrtf(var + 1e-6f);
    bf16_t* o = out + (size_t)row * 768;
    o[t]       = (bf16_t)((v0 - mu) * rstd * w[t]       + b[t]);
    o[t + 256] = (bf16_t)((v1 - mu) * rstd * w[t + 256] + b[t + 256]);
    o[t + 512] = (bf16_t)((v2 - mu) * rstd * w[t + 512] + b[t + 512]);
}

// ---------------- fused QKV GEMM: A[4096][768] @ W[2304][768]^T -------------
// cols 0..1535 -> QK[token][1536]; cols 1536..2303 -> VT[col-1536][4096]
__global__ __launch_bounds__(256, 3) void gemm_qkv_kernel(const bf16_t* __restrict__ A,
                                                          const bf16_t* __restrict__ W,
                                                          bf16_t* __restrict__ outQK,
                                                          bf16_t* __restrict__ outVT) {
    __shared__ bf16_t Alds[128 * 64];
    __shared__ bf16_t Blds[128 * 64];
    const int K = 768, GX = 18;
    const int tid = threadIdx.x;
    const int f = blockIdx.x + GX * blockIdx.y;
    const int slot = f >> 3;
    const int bm = (f & 7) * 4 + slot / GX, bn = slot % GX;
    const int lane = tid & 63, wid = tid >> 6;
    const int wm = wid >> 1, wn = wid & 1;
    const int l15 = lane & 15, lh = lane >> 4;
    f32x4 acc[4][4] = {};

    const int lr = lane >> 3;              // row within 8-row segment
    const int lc = ((lane & 7) ^ lr) * 8;  // pre-swizzled source chunk (elements)
    const bf16_t* gA = A + (size_t)(bm * 128 + lr) * K + lc;
    const bf16_t* gB = W + (size_t)(bn * 128 + lr) * K + lc;

    for (int k0 = 0; k0 < K; k0 += 64) {
        __syncthreads();
#pragma unroll
        for (int q = 0; q < 4; ++q) {
            int r0 = (wid * 4 + q) * 8;
            gload16(gA + (size_t)r0 * K + k0, &Alds[r0 * 64]);
            gload16(gB + (size_t)r0 * K + k0, &Blds[r0 * 64]);
        }
        __syncthreads();
#pragma unroll
        for (int kk = 0; kk < 2; ++kk) {
            bf16x8 av[4], bv[4];
#pragma unroll
            for (int i = 0; i < 4; ++i) {
                int rA = wm * 64 + i * 16 + l15;
                int cc = kk * 4 + lh;
                av[i] = *(const bf16x8*)&Alds[rA * 64 + ((cc ^ (rA & 7)) * 8)];
                int rB = wn * 64 + i * 16 + l15;
                bv[i] = *(const bf16x8*)&Blds[rB * 64 + ((cc ^ (rB & 7)) * 8)];
            }
#pragma unroll
            for (int i = 0; i < 4; ++i)
#pragma unroll
                for (int j = 0; j < 4; ++j)
                    acc[i][j] = __builtin_amdgcn_mfma_f32_16x16x32_bf16(av[i], bv[j], acc[i][j], 0, 0, 0);
        }
    }
#pragma unroll
    for (int i = 0; i < 4; ++i) {
        int row0 = bm * 128 + wm * 64 + i * 16 + lh * 4;
#pragma unroll
        for (int j = 0; j < 4; ++j) {
            int col = bn * 128 + wn * 64 + j * 16 + l15;
            if (col < 1536) {  // uniform per bn-block (1536 % 128 == 0)
#pragma unroll
                for (int p = 0; p < 4; ++p)
                    outQK[(size_t)(row0 + p) * 1536 + col] = (bf16_t)acc[i][j][p];
            } else {
                bf16x4 pk;
#pragma unroll
                for (int p = 0; p < 4; ++p) pk[p] = (bf16_t)acc[i][j][p];
                *(bf16x4*)&outVT[(size_t)(col - 1536) * NTOK + row0] = pk;
            }
        }
    }
}

// ---------------- mlp1 GEMM + GELU: A[4096][768] @ W[3072][768]^T -> bf16 ---
__global__ __launch_bounds__(256, 3) void gemm_gelu_kernel(const bf16_t* __restrict__ A,
                                                           const bf16_t* __restrict__ W,
                                                           const float* __restrict__ bias,
                                                           bf16_t* __restrict__ outB) {
    __shared__ bf16_t Alds[128 * 64];
    __shared__ bf16_t Blds[128 * 64];
    const int K = 768, N = 3072, GX = 24;
    const int tid = threadIdx.x;
    const int f = blockIdx.x + GX * blockIdx.y;
    const int slot = f >> 3;
    const int bm = (f & 7) * 4 + slot / GX, bn = slot % GX;
    const int lane = tid & 63, wid = tid >> 6;
    const int wm = wid >> 1, wn = wid & 1;
    const int l15 = lane & 15, lh = lane >> 4;
    f32x4 acc[4][4] = {};

    const int lr = lane >> 3;
    const int lc = ((lane & 7) ^ lr) * 8;
    const bf16_t* gA = A + (size_t)(bm * 128 + lr) * K + lc;
    const bf16_t* gB = W + (size_t)(bn * 128 + lr) * K + lc;

    for (int k0 = 0; k0 < K; k0 += 64) {
        __syncthreads();
#pragma unroll
        for (int q = 0; q < 4; ++q) {
            int r0 = (wid * 4 + q) * 8;
            gload16(gA + (size_t)r0 * K + k0, &Alds[r0 * 64]);
            gload16(gB + (size_t)r0 * K + k0, &Blds[r0 * 64]);
        }
        __syncthreads();
#pragma unroll
        for (int kk = 0; kk < 2; ++kk) {
            bf16x8 av[4], bv[4];
#pragma unroll
            for (int i = 0; i < 4; ++i) {
                int rA = wm * 64 + i * 16 + l15;
                int cc = kk * 4 + lh;
                av[i] = *(const bf16x8*)&Alds[rA * 64 + ((cc ^ (rA & 7)) * 8)];
                int rB = wn * 64 + i * 16 + l15;
                bv[i] = *(const bf16x8*)&Blds[rB * 64 + ((cc ^ (rB & 7)) * 8)];
            }
#pragma unroll
            for (int i = 0; i < 4; ++i)
#pragma unroll
                for (int j = 0; j < 4; ++j)
                    acc[i][j] = __builtin_amdgcn_mfma_f32_16x16x32_bf16(av[i], bv[j], acc[i][j], 0, 0, 0);
        }
    }
#pragma unroll
    for (int i = 0; i < 4; ++i) {
        int row0 = bm * 128 + wm * 64 + i * 16 + lh * 4;
#pragma unroll
        for (int j = 0; j < 4; ++j) {
            int col = bn * 128 + wn * 64 + j * 16 + l15;
            float bv_ = bias[col];
#pragma unroll
            for (int p = 0; p < 4; ++p) {
                float v = acc[i][j][p] + bv_;
                v = 0.5f * v * (1.f + erff(v * 0.70710678118654752f));
                outB[(size_t)(row0 + p) * N + col] = (bf16_t)v;
            }
        }
    }
}

// ---------------- BN=64 GEMM: C[4096][768] = A[4096][K] @ W[768][K]^T + bias + res
__global__ __launch_bounds__(256, 4) void gemm64_kernel(const bf16_t* __restrict__ A,
                                                        const bf16_t* __restrict__ W,
                                                        const float* __restrict__ bias,
                                                        const float* __restrict__ res,
                                                        float* __restrict__ outF,
                                                        int K) {
    __shared__ bf16_t Alds[128 * 64];
    __shared__ bf16_t Blds[64 * 64];
    const int N = 768, GX = 12;
    const int tid = threadIdx.x;
    const int f = blockIdx.x + GX * blockIdx.y;
    const int slot = f >> 3;
    const int bm = (f & 7) * 4 + slot / GX, bn = slot % GX;
    const int lane = tid & 63, wid = tid >> 6;
    const int l15 = lane & 15, lh = lane >> 4;
    f32x4 acc[2][4] = {};

    const int lr = lane >> 3;
    const int lc = ((lane & 7) ^ lr) * 8;
    const bf16_t* gA = A + (size_t)(bm * 128 + lr) * K + lc;
    const bf16_t* gB = W + (size_t)(bn * 64 + lr) * K + lc;

    for (int k0 = 0; k0 < K; k0 += 64) {
        __syncthreads();
#pragma unroll
        for (int q = 0; q < 4; ++q) {
            int r0 = (wid * 4 + q) * 8;
            gload16(gA + (size_t)r0 * K + k0, &Alds[r0 * 64]);
        }
#pragma unroll
        for (int q = 0; q < 2; ++q) {
            int r0 = (wid * 2 + q) * 8;
            gload16(gB + (size_t)r0 * K + k0, &Blds[r0 * 64]);
        }
        __syncthreads();
#pragma unroll
        for (int kk = 0; kk < 2; ++kk) {
            bf16x8 av[2], bv[4];
#pragma unroll
            for (int i = 0; i < 2; ++i) {
                int rA = wid * 32 + i * 16 + l15;
                int cc = kk * 4 + lh;
                av[i] = *(const bf16x8*)&Alds[rA * 64 + ((cc ^ (rA & 7)) * 8)];
            }
#pragma unroll
            for (int j = 0; j < 4; ++j) {
                int rB = j * 16 + l15;
                int cc = kk * 4 + lh;
                bv[j] = *(const bf16x8*)&Blds[rB * 64 + ((cc ^ (rB & 7)) * 8)];
            }
#pragma unroll
            for (int i = 0; i < 2; ++i)
#pragma unroll
                for (int j = 0; j < 4; ++j)
                    acc[i][j] = __builtin_amdgcn_mfma_f32_16x16x32_bf16(av[i], bv[j], acc[i][j], 0, 0, 0);
        }
    }
#pragma unroll
    for (int i = 0; i < 2; ++i) {
        int row0 = bm * 128 + wid * 32 + i * 16 + lh * 4;
#pragma unroll
        for (int j = 0; j < 4; ++j) {
            int col = bn * 64 + j * 16 + l15;
            float bv_ = bias[col];
#pragma unroll
            for (int p = 0; p < 4; ++p) {
                size_t idx = (size_t)(row0 + p) * N + col;
                outF[idx] = acc[i][j][p] + bv_ + res[idx];
            }
        }
    }
}

// ---------------- MFMA flash attention, QBLK=64, double-buffered K/V --------
// grid (16, 48) -> 768 blocks = 3/CU. XCD remap: xcd = f&7 owns 6 bh pairs.
// Pipeline: stage(t+1) issued BEFORE compute(t); one __syncthreads per tile
// (its vmcnt/lgkm drain lands after a full compute phase -> stall hidden).
__global__ __launch_bounds__(256, 3) void attn_mfma_kernel(const bf16_t* __restrict__ Qp,
                                                           const bf16_t* __restrict__ Kp,
                                                           const bf16_t* __restrict__ VTp,
                                                           bf16_t* __restrict__ Op,
                                                           int ldQ, int ldK,
                                                           int hsQ, int hsK,
                                                           float scale) {
    __shared__ bf16_t Kl[2][64 * 64];
    __shared__ bf16_t Vl[2][64 * 64];
    __shared__ bf16_t Pl[4][16 * 64];
    const int tid = threadIdx.x, lane = tid & 63, w = tid >> 6;
    const int l15 = lane & 15, lh = lane >> 4;
    const int f = blockIdx.x + (blockIdx.y << 4);
    const int slot = f >> 3;                  // 0..95 within XCD
    const int bh = (f & 7) * 6 + (slot >> 4); // 6 bh per XCD
    const int q0 = (slot & 15) * 64;
    const int b = bh / 12, h = bh % 12;

    const bf16_t* qptr = Qp + (size_t)(b * 1024 + q0 + w * 16 + l15) * ldQ + h * hsQ + lh * 8;
    bf16x8 qf0 = *(const bf16x8*)qptr;
    bf16x8 qf1 = *(const bf16x8*)(qptr + 32);

    f32x4 oacc[4] = {};
    float m_run[4], l_run[4];
#pragma unroll
    for (int p = 0; p < 4; ++p) { m_run[p] = -1e30f; l_run[p] = 0.f; }

    const int lr = lane >> 3;              // row within 8-row staging segment
    const int lc = ((lane & 7) ^ lr) * 8;  // pre-swizzled source chunk
    const bf16_t* kbase = Kp + (size_t)(b * 1024 + lr) * ldK + h * hsK + lc;
    const bf16_t* vbase = VTp + (size_t)(h * 64 + lr) * NTOK + b * 1024 + lc;

    // stage tile kt into buffer bb: per wave 2 segments of 8 rows
    auto stage = [&](int bb, int kt) {
#pragma unroll
        for (int q = 0; q < 2; ++q) {
            int r0 = (w * 2 + q) * 8;
            gload16(kbase + (size_t)(kt + r0) * ldK, &Kl[bb][r0 * 64]);
            gload16(vbase + (size_t)r0 * NTOK + kt, &Vl[bb][r0 * 64]);
        }
    };

    stage(0, 0);
    __syncthreads();  // drains prologue loads

    for (int it = 0; it < 16; ++it) {
        const int cur = it & 1;
        if (it < 15) stage(cur ^ 1, (it + 1) * 64);  // prefetch next tile

        // ---- QK^T: 16 q-rows x 64 keys from Kl[cur] ----
        f32x4 s[4] = {};
#pragma unroll
        for (int t = 0; t < 4; ++t) {
            int key = t * 16 + l15;
            bf16x8 kf0 = *(const bf16x8*)&Kl[cur][key * 64 + ((lh ^ (key & 7)) * 8)];
            bf16x8 kf1 = *(const bf16x8*)&Kl[cur][key * 64 + (((4 + lh) ^ (key & 7)) * 8)];
            s[t] = __builtin_amdgcn_mfma_f32_16x16x32_bf16(qf0, kf0, s[t], 0, 0, 0);
            s[t] = __builtin_amdgcn_mfma_f32_16x16x32_bf16(qf1, kf1, s[t], 0, 0, 0);
        }

        // ---- online softmax; lane owns rows r = lh*4+p, key col = t*16+l15 ----
#pragma unroll
        for (int p = 0; p < 4; ++p) {
            float v0 = s[0][p] * scale, v1 = s[1][p] * scale;
            float v2 = s[2][p] * scale, v3 = s[3][p] * scale;
            float mloc = fmaxf(fmaxf(v0, v1), fmaxf(v2, v3));
#pragma unroll
            for (int off = 1; off < 16; off <<= 1) mloc = fmaxf(mloc, __shfl_xor(mloc, off));
            float mnew = fmaxf(m_run[p], mloc);
            float corr = __expf(m_run[p] - mnew);
            float p0 = __expf(v0 - mnew), p1 = __expf(v1 - mnew);
            float p2 = __expf(v2 - mnew), p3 = __expf(v3 - mnew);
            float ps = p0 + p1 + p2 + p3;
#pragma unroll
            for (int off = 1; off < 16; off <<= 1) ps += __shfl_xor(ps, off);
            l_run[p] = l_run[p] * corr + ps;
            m_run[p] = mnew;
            oacc[0][p] *= corr; oacc[1][p] *= corr; oacc[2][p] *= corr; oacc[3][p] *= corr;
            int r = lh * 4 + p;
            bf16_t* pr = &Pl[w][r * 64];
            int cb = l15 >> 3, ce = l15 & 7, rs = r & 7;
            pr[((0 + cb) ^ rs) * 8 + ce] = (bf16_t)p0;
            pr[((2 + cb) ^ rs) * 8 + ce] = (bf16_t)p1;
            pr[((4 + cb) ^ rs) * 8 + ce] = (bf16_t)p2;
            pr[((6 + cb) ^ rs) * 8 + ce] = (bf16_t)p3;
        }

        // ---- PV from Vl[cur] (same-wave Pl write->read) ----
#pragma unroll
        for (int kk = 0; kk < 2; ++kk) {
            bf16x8 pf = *(const bf16x8*)&Pl[w][l15 * 64 + (((kk * 4 + lh) ^ (l15 & 7)) * 8)];
#pragma unroll
            for (int dt = 0; dt < 4; ++dt) {
                int d = dt * 16 + l15;
                bf16x8 vf = *(const bf16x8*)&Vl[cur][d * 64 + (((kk * 4 + lh) ^ (d & 7)) * 8)];
                oacc[dt] = __builtin_amdgcn_mfma_f32_16x16x32_bf16(pf, vf, oacc[dt], 0, 0, 0);
            }
        }

        __syncthreads();  // next tile's loads completed; all waves done with [cur]
    }

    float inv[4];
#pragma unroll
    for (int p = 0; p < 4; ++p) inv[p] = 1.f / l_run[p];
#pragma unroll
    for (int dt = 0; dt < 4; ++dt) {
#pragma unroll
        for (int p = 0; p < 4; ++p) {
            int row = q0 + w * 16 + lh * 4 + p;
            int col = h * 64 + dt * 16 + l15;
            Op[(size_t)(b * 1024 + row) * 768 + col] = (bf16_t)(oacc[dt][p] * inv[p]);
        }
    }
}

// ------------------------------------------------------------------
extern "C" void kernel_launch(void* const* d_in, const int* in_sizes, int n_in,
                              void* d_out, int out_size, void* d_ws, size_t ws_size,
                              hipStream_t stream) {
    const float* x_in   = (const float*)d_in[0];
    const float* src_in = (const float*)d_in[1];
    const float* b_proj   = (const float*)d_in[4];
    const float* b_proj_s = (const float*)d_in[7];
    const float* b_cp     = (const float*)d_in[13];
    const float* b_cp_s   = (const float*)d_in[15];
    const float* mlp1_b   = (const float*)d_in[17];
    const float* mlp2_b   = (const float*)d_in[19];
    const float* mlp1s_b  = (const float*)d_in[21];
    const float* mlp2s_b  = (const float*)d_in[23];
    const float* ln1_w  = (const float*)d_in[24];
    const float* ln1_b  = (const float*)d_in[25];
    const float* ln1s_w = (const float*)d_in[26];
    const float* ln1s_b = (const float*)d_in[27];
    const float* lnc_w  = (const float*)d_in[28];
    const float* lnc_b  = (const float*)d_in[29];
    const float* lncs_w = (const float*)d_in[30];
    const float* lncs_b = (const float*)d_in[31];
    const float* ln2_w  = (const float*)d_in[32];
    const float* ln2_b  = (const float*)d_in[33];
    const float* ln2s_w = (const float*)d_in[34];
    const float* ln2s_b = (const float*)d_in[35];

    char* ws = (char*)d_ws;
    size_t off = 0;
    auto alloc = [&](size_t bytes) -> void* {
        void* p = ws + off;
        off = (off + bytes + 255) & ~(size_t)255;
        return p;
    };

    bf16_t* bw_qkv_x = (bf16_t*)alloc((size_t)2304 * 768 * 2);
    bf16_t* bw_proj_x = (bf16_t*)alloc((size_t)768 * 768 * 2);
    bf16_t* bw_qkv_s = (bf16_t*)alloc((size_t)2304 * 768 * 2);
    bf16_t* bw_proj_s = (bf16_t*)alloc((size_t)768 * 768 * 2);
    bf16_t* bw_cx    = (bf16_t*)alloc((size_t)2304 * 768 * 2);  // [w_qk; w_v]
    bf16_t* bw_cs    = (bf16_t*)alloc((size_t)2304 * 768 * 2);  // [w_qk_src; w_v_src]
    bf16_t* bw_cp    = (bf16_t*)alloc((size_t)768 * 768 * 2);
    bf16_t* bw_cp_s  = (bf16_t*)alloc((size_t)768 * 768 * 2);
    bf16_t* bw_mlp1  = (bf16_t*)alloc((size_t)3072 * 768 * 2);
    bf16_t* bw_mlp2  = (bf16_t*)alloc((size_t)768 * 3072 * 2);
    bf16_t* bw_mlp1s = (bf16_t*)alloc((size_t)3072 * 768 * 2);
    bf16_t* bw_mlp2s = (bf16_t*)alloc((size_t)768 * 3072 * 2);

    bf16_t* arena = (bf16_t*)alloc((size_t)NTOK * 3072 * 2 * 2);
    bf16_t* LN_A = (bf16_t*)alloc((size_t)NTOK * 768 * 2);
    bf16_t* LN_B = (bf16_t*)alloc((size_t)NTOK * 768 * 2);
    bf16_t* O_A  = (bf16_t*)alloc((size_t)NTOK * 768 * 2);
    bf16_t* O_B  = (bf16_t*)alloc((size_t)NTOK * 768 * 2);

    float* Xst = (float*)d_out;
    float* Sst = (float*)d_out + (size_t)NTOK * 768;

    bf16_t* SQK = arena;                               // self: [4096][1536]
    bf16_t* VTs = arena + (size_t)NTOK * 1536;         // self: [768][4096]
    bf16_t* QKx = arena;                               // cross: [4096][1536]
    bf16_t* QKs = arena + (size_t)NTOK * 1536;
    bf16_t* VxT = arena + (size_t)NTOK * 3072;         // cross: [768][4096]
    bf16_t* VsT = arena + (size_t)NTOK * 3072 + (size_t)768 * NTOK;
    bf16_t* H_A = arena;                               // mlp: [4096][3072]
    bf16_t* H_B = arena + (size_t)NTOK * 3072;

    CvtTab tab;
    const float* csrc[14] = {(const float*)d_in[2], (const float*)d_in[3],
                             (const float*)d_in[5], (const float*)d_in[6],
                             (const float*)d_in[8], (const float*)d_in[10],
                             (const float*)d_in[9], (const float*)d_in[11],
                             (const float*)d_in[12], (const float*)d_in[14],
                             (const float*)d_in[16], (const float*)d_in[18],
                             (const float*)d_in[20], (const float*)d_in[22]};
    bf16_t* cdst[14] = {bw_qkv_x, bw_proj_x, bw_qkv_s, bw_proj_s,
                        bw_cx, bw_cx + (size_t)1536 * 768,
                        bw_cs, bw_cs + (size_t)1536 * 768,
                        bw_cp, bw_cp_s, bw_mlp1, bw_mlp2, bw_mlp1s, bw_mlp2s};
    int cn[14] = {2304 * 768, 768 * 768, 2304 * 768, 768 * 768,
                  1536 * 768, 768 * 768, 1536 * 768, 768 * 768,
                  768 * 768, 768 * 768, 3072 * 768, 768 * 3072, 3072 * 768, 768 * 3072};
    for (int i = 0; i < 14; ++i) { tab.src[i] = csrc[i]; tab.dst[i] = cdst[i]; tab.n[i] = cn[i]; }
    cvt_all_kernel<<<dim3(1152, 14), 256, 0, stream>>>(tab);

    const dim3 blk(256);
    const dim3 qkv_grid(18, 32);
    const dim3 g64_grid(12, 32);
    const dim3 gelu_grid(24, 32);
    const dim3 attn_grid(16, 48);

    // ---- x self-attention ----
    ln_kernel<<<NTOK, blk, 0, stream>>>(x_in, ln1_w, ln1_b, LN_A);
    gemm_qkv_kernel<<<qkv_grid, blk, 0, stream>>>(LN_A, bw_qkv_x, SQK, VTs);
    attn_mfma_kernel<<<attn_grid, blk, 0, stream>>>(SQK, SQK + 768, VTs, O_A, 1536, 1536, 64, 64, SCALE_ATTN);
    gemm64_kernel<<<g64_grid, blk, 0, stream>>>(O_A, bw_proj_x, b_proj, x_in, Xst, 768);

    // ---- src self-attention ----
    ln_kernel<<<NTOK, blk, 0, stream>>>(src_in, ln1s_w, ln1s_b, LN_A);
    gemm_qkv_kernel<<<qkv_grid, blk, 0, stream>>>(LN_A, bw_qkv_s, SQK, VTs);
    attn_mfma_kernel<<<attn_grid, blk, 0, stream>>>(SQK, SQK + 768, VTs, O_A, 1536, 1536, 64, 64, SCALE_ATTN);
    gemm64_kernel<<<g64_grid, blk, 0, stream>>>(O_A, bw_proj_s, b_proj_s, src_in, Sst, 768);

    // ---- cross attention ----
    ln_kernel<<<NTOK, blk, 0, stream>>>(Xst, lnc_w, lnc_b, LN_A);
    ln_kernel<<<NTOK, blk, 0, stream>>>(Sst, lncs_w, lncs_b, LN_B);
    gemm_qkv_kernel<<<qkv_grid, blk, 0, stream>>>(LN_A, bw_cx, QKx, VxT);
    gemm_qkv_kernel<<<qkv_grid, blk, 0, stream>>>(LN_B, bw_cs, QKs, VsT);
    // y   = softmax(q · q_s) @ v_s
    attn_mfma_kernel<<<attn_grid, blk, 0, stream>>>(QKx, QKs, VsT, O_A, 1536, 1536, 128, 128, SCALE_ATTN);
    // y_s = softmax(k_s · kx) @ v
    attn_mfma_kernel<<<attn_grid, blk, 0, stream>>>(QKs + 64, QKx + 64, VxT, O_B, 1536, 1536, 128, 128, SCALE_ATTN);
    gemm64_kernel<<<g64_grid, blk, 0, stream>>>(O_A, bw_cp, b_cp, Xst, Xst, 768);
    gemm64_kernel<<<g64_grid, blk, 0, stream>>>(O_B, bw_cp_s, b_cp_s, Sst, Sst, 768);

    // ---- MLPs ----
    ln_kernel<<<NTOK, blk, 0, stream>>>(Xst, ln2_w, ln2_b, LN_A);
    ln_kernel<<<NTOK, blk, 0, stream>>>(Sst, ln2s_w, ln2s_b, LN_B);
    gemm_gelu_kernel<<<gelu_grid, blk, 0, stream>>>(LN_A, bw_mlp1, mlp1_b, H_A);
    gemm_gelu_kernel<<<gelu_grid, blk, 0, stream>>>(LN_B, bw_mlp1s, mlp1s_b, H_B);
    gemm64_kernel<<<g64_grid, blk, 0, stream>>>(H_A, bw_mlp2, mlp2_b, Xst, Xst, 3072);
    gemm64_kernel<<<g64_grid, blk, 0, stream>>>(H_B, bw_mlp2s, mlp2s_b, Sst, Sst, 3072);
}

// Round 10
// 609.783 us; speedup vs baseline: 3.5737x; 1.1098x over previous
//
#include <hip/hip_runtime.h>
#include <hip/hip_bf16.h>
#include <cmath>

// CrossAttentionTransformerBlock: B=4, N=M=1024, C=768, H=12, HD=64, HID=3072
// Round 10: resubmit of round-8 kernel (two consecutive infra failures).
// Swapped-operand attention softmax (T12), 64x64 dbuf gemm64 (3 blocks/CU).

typedef __bf16 bf16_t;
typedef __attribute__((ext_vector_type(8))) __bf16 bf16x8;
typedef __attribute__((ext_vector_type(4))) __bf16 bf16x4;
typedef __attribute__((ext_vector_type(4))) float f32x4;

#define NTOK 4096          // B*N rows
#define SCALE_ATTN 0.125f  // HD^-0.5

// global -> LDS direct DMA, 16B/lane. LDS dest must be wave-uniform;
// per-lane global src carries the swizzle (guide §5 caveat, m104/m173).
__device__ __forceinline__ void gload16(const void* g, void* l) {
    __builtin_amdgcn_global_load_lds((const __attribute__((address_space(1))) void*)g,
                                     (__attribute__((address_space(3))) void*)l, 16, 0, 0);
}

// ---------------- mega f32->bf16 conversion (14 segments, one launch) -------
struct CvtTab {
    const float* src[14];
    bf16_t* dst[14];
    int n[14];
};
__global__ __launch_bounds__(256) void cvt_all_kernel(CvtTab t) {
    int seg = blockIdx.y;
    int base = blockIdx.x * 2048 + threadIdx.x * 8;
    if (base >= t.n[seg]) return;
    const float* s = t.src[seg];
    float4 a = *(const float4*)(s + base);
    float4 b = *(const float4*)(s + base + 4);
    bf16x8 o;
    o[0] = (bf16_t)a.x; o[1] = (bf16_t)a.y; o[2] = (bf16_t)a.z; o[3] = (bf16_t)a.w;
    o[4] = (bf16_t)b.x; o[5] = (bf16_t)b.y; o[6] = (bf16_t)b.z; o[7] = (bf16_t)b.w;
    *(bf16x8*)(t.dst[seg] + base) = o;
}

// ---------------- LayerNorm over C=768, f32 in -> bf16 out ----------------
__global__ __launch_bounds__(256) void ln_kernel(const float* __restrict__ X,
                                                 const float* __restrict__ w,
                                                 const float* __restrict__ b,
                                                 bf16_t* __restrict__ out) {
    int row = blockIdx.x, t = threadIdx.x;
    const float* x = X + (size_t)row * 768;
    float v0 = x[t], v1 = x[t + 256], v2 = x[t + 512];
    float s = v0 + v1 + v2;
    float s2 = v0 * v0 + v1 * v1 + v2 * v2;
#pragma unroll
    for (int off = 32; off > 0; off >>= 1) {
        s += __shfl_down(s, off);
        s2 += __shfl_down(s2, off);
    }
    __shared__ float as_[4], as2_[4];
    int wave = t >> 6;
    if ((t & 63) == 0) { as_[wave] = s; as2_[wave] = s2; }
    __syncthreads();
    float tot = as_[0] + as_[1] + as_[2] + as_[3];
    float tot2 = as2_[0] + as2_[1] + as2_[2] + as2_[3];
    float mu = tot * (1.f / 768.f);
    float var = tot2 * (1.f / 768.f) - mu * mu;
    float rstd = rsqrtf(var + 1e-6f);
    bf16_t* o = out + (size_t)row * 768;
    o[t]       = (bf16_t)((v0 - mu) * rstd * w[t]       + b[t]);
    o[t + 256] = (bf16_t)((v1 - mu) * rstd * w[t + 256] + b[t + 256]);
    o[t + 512] = (bf16_t)((v2 - mu) * rstd * w[t + 512] + b[t + 512]);
}

// ---------------- fused QKV GEMM: A[4096][768] @ W[2304][768]^T -------------
// cols 0..1535 -> QK[token][1536]; cols 1536..2303 -> VT[col-1536][4096]
__global__ __launch_bounds__(256, 3) void gemm_qkv_kernel(const bf16_t* __restrict__ A,
                                                          const bf16_t* __restrict__ W,
                                                          bf16_t* __restrict__ outQK,
                                                          bf16_t* __restrict__ outVT) {
    __shared__ bf16_t Alds[128 * 64];
    __shared__ bf16_t Blds[128 * 64];
    const int K = 768, GX = 18;
    const int tid = threadIdx.x;
    const int f = blockIdx.x + GX * blockIdx.y;
    const int slot = f >> 3;
    const int bm = (f & 7) * 4 + slot / GX, bn = slot % GX;
    const int lane = tid & 63, wid = tid >> 6;
    const int wm = wid >> 1, wn = wid & 1;
    const int l15 = lane & 15, lh = lane >> 4;
    f32x4 acc[4][4] = {};

    const int lr = lane >> 3;              // row within 8-row segment
    const int lc = ((lane & 7) ^ lr) * 8;  // pre-swizzled source chunk (elements)
    const bf16_t* gA = A + (size_t)(bm * 128 + lr) * K + lc;
    const bf16_t* gB = W + (size_t)(bn * 128 + lr) * K + lc;

    for (int k0 = 0; k0 < K; k0 += 64) {
        __syncthreads();
#pragma unroll
        for (int q = 0; q < 4; ++q) {
            int r0 = (wid * 4 + q) * 8;
            gload16(gA + (size_t)r0 * K + k0, &Alds[r0 * 64]);
            gload16(gB + (size_t)r0 * K + k0, &Blds[r0 * 64]);
        }
        __syncthreads();
#pragma unroll
        for (int kk = 0; kk < 2; ++kk) {
            bf16x8 av[4], bv[4];
#pragma unroll
            for (int i = 0; i < 4; ++i) {
                int rA = wm * 64 + i * 16 + l15;
                int cc = kk * 4 + lh;
                av[i] = *(const bf16x8*)&Alds[rA * 64 + ((cc ^ (rA & 7)) * 8)];
                int rB = wn * 64 + i * 16 + l15;
                bv[i] = *(const bf16x8*)&Blds[rB * 64 + ((cc ^ (rB & 7)) * 8)];
            }
#pragma unroll
            for (int i = 0; i < 4; ++i)
#pragma unroll
                for (int j = 0; j < 4; ++j)
                    acc[i][j] = __builtin_amdgcn_mfma_f32_16x16x32_bf16(av[i], bv[j], acc[i][j], 0, 0, 0);
        }
    }
#pragma unroll
    for (int i = 0; i < 4; ++i) {
        int row0 = bm * 128 + wm * 64 + i * 16 + lh * 4;
#pragma unroll
        for (int j = 0; j < 4; ++j) {
            int col = bn * 128 + wn * 64 + j * 16 + l15;
            if (col < 1536) {  // uniform per bn-block (1536 % 128 == 0)
#pragma unroll
                for (int p = 0; p < 4; ++p)
                    outQK[(size_t)(row0 + p) * 1536 + col] = (bf16_t)acc[i][j][p];
            } else {
                bf16x4 pk;
#pragma unroll
                for (int p = 0; p < 4; ++p) pk[p] = (bf16_t)acc[i][j][p];
                *(bf16x4*)&outVT[(size_t)(col - 1536) * NTOK + row0] = pk;
            }
        }
    }
}

// ---------------- mlp1 GEMM + GELU: A[4096][768] @ W[3072][768]^T -> bf16 ---
__global__ __launch_bounds__(256, 3) void gemm_gelu_kernel(const bf16_t* __restrict__ A,
                                                           const bf16_t* __restrict__ W,
                                                           const float* __restrict__ bias,
                                                           bf16_t* __restrict__ outB) {
    __shared__ bf16_t Alds[128 * 64];
    __shared__ bf16_t Blds[128 * 64];
    const int K = 768, N = 3072, GX = 24;
    const int tid = threadIdx.x;
    const int f = blockIdx.x + GX * blockIdx.y;
    const int slot = f >> 3;
    const int bm = (f & 7) * 4 + slot / GX, bn = slot % GX;
    const int lane = tid & 63, wid = tid >> 6;
    const int wm = wid >> 1, wn = wid & 1;
    const int l15 = lane & 15, lh = lane >> 4;
    f32x4 acc[4][4] = {};

    const int lr = lane >> 3;
    const int lc = ((lane & 7) ^ lr) * 8;
    const bf16_t* gA = A + (size_t)(bm * 128 + lr) * K + lc;
    const bf16_t* gB = W + (size_t)(bn * 128 + lr) * K + lc;

    for (int k0 = 0; k0 < K; k0 += 64) {
        __syncthreads();
#pragma unroll
        for (int q = 0; q < 4; ++q) {
            int r0 = (wid * 4 + q) * 8;
            gload16(gA + (size_t)r0 * K + k0, &Alds[r0 * 64]);
            gload16(gB + (size_t)r0 * K + k0, &Blds[r0 * 64]);
        }
        __syncthreads();
#pragma unroll
        for (int kk = 0; kk < 2; ++kk) {
            bf16x8 av[4], bv[4];
#pragma unroll
            for (int i = 0; i < 4; ++i) {
                int rA = wm * 64 + i * 16 + l15;
                int cc = kk * 4 + lh;
                av[i] = *(const bf16x8*)&Alds[rA * 64 + ((cc ^ (rA & 7)) * 8)];
                int rB = wn * 64 + i * 16 + l15;
                bv[i] = *(const bf16x8*)&Blds[rB * 64 + ((cc ^ (rB & 7)) * 8)];
            }
#pragma unroll
            for (int i = 0; i < 4; ++i)
#pragma unroll
                for (int j = 0; j < 4; ++j)
                    acc[i][j] = __builtin_amdgcn_mfma_f32_16x16x32_bf16(av[i], bv[j], acc[i][j], 0, 0, 0);
        }
    }
#pragma unroll
    for (int i = 0; i < 4; ++i) {
        int row0 = bm * 128 + wm * 64 + i * 16 + lh * 4;
#pragma unroll
        for (int j = 0; j < 4; ++j) {
            int col = bn * 128 + wn * 64 + j * 16 + l15;
            float bv_ = bias[col];
#pragma unroll
            for (int p = 0; p < 4; ++p) {
                float v = acc[i][j][p] + bv_;
                v = 0.5f * v * (1.f + erff(v * 0.70710678118654752f));
                outB[(size_t)(row0 + p) * N + col] = (bf16_t)v;
            }
        }
    }
}

// ---------------- 64x64 GEMM, dbuf: C[4096][768] = A[4096][K] @ W[768][K]^T + bias + res
// grid (12, 64) = 768 blocks = 3/CU. 4 waves in 2x2 of 32x32 tiles.
__global__ __launch_bounds__(256, 4) void gemm64_kernel(const bf16_t* __restrict__ A,
                                                        const bf16_t* __restrict__ W,
                                                        const float* __restrict__ bias,
                                                        const float* __restrict__ res,
                                                        float* __restrict__ outF,
                                                        int K) {
    __shared__ bf16_t Alds[2][64 * 64];
    __shared__ bf16_t Blds[2][64 * 64];
    const int N = 768, GX = 12;
    const int tid = threadIdx.x;
    const int f = blockIdx.x + GX * blockIdx.y;
    const int slot = f >> 3;                       // 0..95 within XCD
    const int bm = (f & 7) * 8 + slot / GX;        // 64 bm tiles, 8 per XCD
    const int bn = slot % GX;
    const int lane = tid & 63, wid = tid >> 6;
    const int wm = wid >> 1, wn = wid & 1;
    const int l15 = lane & 15, lh = lane >> 4;
    f32x4 acc[2][2] = {};

    const int lr = lane >> 3;
    const int lc = ((lane & 7) ^ lr) * 8;
    const bf16_t* gA = A + (size_t)(bm * 64 + lr) * K + lc;
    const bf16_t* gB = W + (size_t)(bn * 64 + lr) * K + lc;

    auto stage = [&](int bb, int k0) {
#pragma unroll
        for (int q = 0; q < 2; ++q) {
            int r0 = (wid * 2 + q) * 8;
            gload16(gA + (size_t)r0 * K + k0, &Alds[bb][r0 * 64]);
            gload16(gB + (size_t)r0 * K + k0, &Blds[bb][r0 * 64]);
        }
    };

    const int NT = K >> 6;
    stage(0, 0);
    __syncthreads();

    for (int it = 0; it < NT; ++it) {
        const int cur = it & 1;
        if (it + 1 < NT) stage(cur ^ 1, (it + 1) * 64);
#pragma unroll
        for (int kk = 0; kk < 2; ++kk) {
            bf16x8 av[2], bv[2];
            int cc = kk * 4 + lh;
#pragma unroll
            for (int i = 0; i < 2; ++i) {
                int rA = wm * 32 + i * 16 + l15;
                av[i] = *(const bf16x8*)&Alds[cur][rA * 64 + ((cc ^ (rA & 7)) * 8)];
                int rB = wn * 32 + i * 16 + l15;
                bv[i] = *(const bf16x8*)&Blds[cur][rB * 64 + ((cc ^ (rB & 7)) * 8)];
            }
#pragma unroll
            for (int i = 0; i < 2; ++i)
#pragma unroll
                for (int j = 0; j < 2; ++j)
                    acc[i][j] = __builtin_amdgcn_mfma_f32_16x16x32_bf16(av[i], bv[j], acc[i][j], 0, 0, 0);
        }
        __syncthreads();
    }
#pragma unroll
    for (int i = 0; i < 2; ++i) {
        int row0 = bm * 64 + wm * 32 + i * 16 + lh * 4;
#pragma unroll
        for (int j = 0; j < 2; ++j) {
            int col = bn * 64 + wn * 32 + j * 16 + l15;
            float bv_ = bias[col];
#pragma unroll
            for (int p = 0; p < 4; ++p) {
                size_t idx = (size_t)(row0 + p) * N + col;
                outF[idx] = acc[i][j][p] + bv_ + res[idx];
            }
        }
    }
}

// ---------------- MFMA flash attention, swapped operands ----------------
// S^T = mfma(K, Q): lane holds 16 scores of ONE q-row -> in-lane softmax.
// O^T = mfma(V^T, P^T): softmax state stays lane-local. QBLK=64, dbuf K/V.
__global__ __launch_bounds__(256, 3) void attn_mfma_kernel(const bf16_t* __restrict__ Qp,
                                                           const bf16_t* __restrict__ Kp,
                                                           const bf16_t* __restrict__ VTp,
                                                           bf16_t* __restrict__ Op,
                                                           int ldQ, int ldK,
                                                           int hsQ, int hsK,
                                                           float scale) {
    __shared__ bf16_t Kl[2][64 * 64];
    __shared__ bf16_t Vl[2][64 * 64];
    __shared__ bf16_t Pl[4][16 * 64];
    const int tid = threadIdx.x, lane = tid & 63, w = tid >> 6;
    const int l15 = lane & 15, lh = lane >> 4;
    const int f = blockIdx.x + (blockIdx.y << 4);
    const int slot = f >> 3;                  // 0..95 within XCD
    const int bh = (f & 7) * 6 + (slot >> 4); // 6 bh per XCD
    const int q0 = (slot & 15) * 64;
    const int b = bh / 12, h = bh % 12;

    // Q fragment (B-operand): col q = w*16+l15, k-chunks lh*8 (+32)
    const bf16_t* qptr = Qp + (size_t)(b * 1024 + q0 + w * 16 + l15) * ldQ + h * hsQ + lh * 8;
    bf16x8 qf0 = *(const bf16x8*)qptr;
    bf16x8 qf1 = *(const bf16x8*)(qptr + 32);

    f32x4 oacc[4] = {};              // O^T: col q = l15, row d = dt*16+lh*4+p
    float m_run = -1e30f, l_run = 0.f;  // per-lane (q = w*16+l15)

    const int lr = lane >> 3;              // row within 8-row staging segment
    const int lc = ((lane & 7) ^ lr) * 8;  // pre-swizzled source chunk
    const bf16_t* kbase = Kp + (size_t)(b * 1024 + lr) * ldK + h * hsK + lc;
    const bf16_t* vbase = VTp + (size_t)(h * 64 + lr) * NTOK + b * 1024 + lc;

    auto stage = [&](int bb, int kt) {
#pragma unroll
        for (int q = 0; q < 2; ++q) {
            int r0 = (w * 2 + q) * 8;
            gload16(kbase + (size_t)(kt + r0) * ldK, &Kl[bb][r0 * 64]);
            gload16(vbase + (size_t)r0 * NTOK + kt, &Vl[bb][r0 * 64]);
        }
    };

    stage(0, 0);
    __syncthreads();

    for (int it = 0; it < 16; ++it) {
        const int cur = it & 1;
        if (it < 15) stage(cur ^ 1, (it + 1) * 64);

        // ---- S^T = K·Q^T: s[t] rows = keys t*16+lh*4+p, col = q (l15) ----
        f32x4 s[4] = {};
#pragma unroll
        for (int t = 0; t < 4; ++t) {
            int key = t * 16 + l15;
            bf16x8 kf0 = *(const bf16x8*)&Kl[cur][key * 64 + ((lh ^ (key & 7)) * 8)];
            bf16x8 kf1 = *(const bf16x8*)&Kl[cur][key * 64 + (((4 + lh) ^ (key & 7)) * 8)];
            s[t] = __builtin_amdgcn_mfma_f32_16x16x32_bf16(kf0, qf0, s[t], 0, 0, 0);
            s[t] = __builtin_amdgcn_mfma_f32_16x16x32_bf16(kf1, qf1, s[t], 0, 0, 0);
        }

        // ---- in-lane softmax over 16 keys + 2-step shfl across lh groups ----
        float v[4][4];
        float mx = -1e30f;
#pragma unroll
        for (int t = 0; t < 4; ++t)
#pragma unroll
            for (int p = 0; p < 4; ++p) {
                v[t][p] = s[t][p] * scale;
                mx = fmaxf(mx, v[t][p]);
            }
        mx = fmaxf(mx, __shfl_xor(mx, 16));
        mx = fmaxf(mx, __shfl_xor(mx, 32));
        float mnew = fmaxf(m_run, mx);
        float corr = __expf(m_run - mnew);
        m_run = mnew;
        float ps = 0.f;
        const int rs = l15 & 7;
        bf16_t* prow = &Pl[w][l15 * 64];
#pragma unroll
        for (int t = 0; t < 4; ++t) {
            bf16x4 pk;
#pragma unroll
            for (int p = 0; p < 4; ++p) {
                float ev = __expf(v[t][p] - mnew);
                ps += ev;
                pk[p] = (bf16_t)ev;
            }
            // P[q][key]: keys t*16+lh*4..+3 -> chunk c=2t+(lh>>1), sub (lh&1)*4
            int c = 2 * t + (lh >> 1);
            *(bf16x4*)&prow[((c ^ rs) * 8) + (lh & 1) * 4] = pk;
        }
        ps += __shfl_xor(ps, 16);
        ps += __shfl_xor(ps, 32);
        l_run = l_run * corr + ps;
#pragma unroll
        for (int dt = 0; dt < 4; ++dt) oacc[dt] *= corr;

        // ---- O^T += V^T · P^T (same-wave Pl write->read) ----
#pragma unroll
        for (int kk = 0; kk < 2; ++kk) {
            bf16x8 pf = *(const bf16x8*)&prow[(((kk * 4 + lh) ^ rs) * 8)];
#pragma unroll
            for (int dt = 0; dt < 4; ++dt) {
                int d = dt * 16 + l15;
                bf16x8 vf = *(const bf16x8*)&Vl[cur][d * 64 + (((kk * 4 + lh) ^ (d & 7)) * 8)];
                oacc[dt] = __builtin_amdgcn_mfma_f32_16x16x32_bf16(vf, pf, oacc[dt], 0, 0, 0);
            }
        }

        __syncthreads();
    }

    float inv = 1.f / l_run;
    bf16_t* orow = Op + (size_t)(b * 1024 + q0 + w * 16 + l15) * 768 + h * 64;
#pragma unroll
    for (int dt = 0; dt < 4; ++dt) {
        bf16x4 pk;
#pragma unroll
        for (int p = 0; p < 4; ++p) pk[p] = (bf16_t)(oacc[dt][p] * inv);
        *(bf16x4*)&orow[dt * 16 + lh * 4] = pk;
    }
}

// ------------------------------------------------------------------
extern "C" void kernel_launch(void* const* d_in, const int* in_sizes, int n_in,
                              void* d_out, int out_size, void* d_ws, size_t ws_size,
                              hipStream_t stream) {
    const float* x_in   = (const float*)d_in[0];
    const float* src_in = (const float*)d_in[1];
    const float* b_proj   = (const float*)d_in[4];
    const float* b_proj_s = (const float*)d_in[7];
    const float* b_cp     = (const float*)d_in[13];
    const float* b_cp_s   = (const float*)d_in[15];
    const float* mlp1_b   = (const float*)d_in[17];
    const float* mlp2_b   = (const float*)d_in[19];
    const float* mlp1s_b  = (const float*)d_in[21];
    const float* mlp2s_b  = (const float*)d_in[23];
    const float* ln1_w  = (const float*)d_in[24];
    const float* ln1_b  = (const float*)d_in[25];
    const float* ln1s_w = (const float*)d_in[26];
    const float* ln1s_b = (const float*)d_in[27];
    const float* lnc_w  = (const float*)d_in[28];
    const float* lnc_b  = (const float*)d_in[29];
    const float* lncs_w = (const float*)d_in[30];
    const float* lncs_b = (const float*)d_in[31];
    const float* ln2_w  = (const float*)d_in[32];
    const float* ln2_b  = (const float*)d_in[33];
    const float* ln2s_w = (const float*)d_in[34];
    const float* ln2s_b = (const float*)d_in[35];

    char* ws = (char*)d_ws;
    size_t off = 0;
    auto alloc = [&](size_t bytes) -> void* {
        void* p = ws + off;
        off = (off + bytes + 255) & ~(size_t)255;
        return p;
    };

    bf16_t* bw_qkv_x = (bf16_t*)alloc((size_t)2304 * 768 * 2);
    bf16_t* bw_proj_x = (bf16_t*)alloc((size_t)768 * 768 * 2);
    bf16_t* bw_qkv_s = (bf16_t*)alloc((size_t)2304 * 768 * 2);
    bf16_t* bw_proj_s = (bf16_t*)alloc((size_t)768 * 768 * 2);
    bf16_t* bw_cx    = (bf16_t*)alloc((size_t)2304 * 768 * 2);  // [w_qk; w_v]
    bf16_t* bw_cs    = (bf16_t*)alloc((size_t)2304 * 768 * 2);  // [w_qk_src; w_v_src]
    bf16_t* bw_cp    = (bf16_t*)alloc((size_t)768 * 768 * 2);
    bf16_t* bw_cp_s  = (bf16_t*)alloc((size_t)768 * 768 * 2);
    bf16_t* bw_mlp1  = (bf16_t*)alloc((size_t)3072 * 768 * 2);
    bf16_t* bw_mlp2  = (bf16_t*)alloc((size_t)768 * 3072 * 2);
    bf16_t* bw_mlp1s = (bf16_t*)alloc((size_t)3072 * 768 * 2);
    bf16_t* bw_mlp2s = (bf16_t*)alloc((size_t)768 * 3072 * 2);

    bf16_t* arena = (bf16_t*)alloc((size_t)NTOK * 3072 * 2 * 2);
    bf16_t* LN_A = (bf16_t*)alloc((size_t)NTOK * 768 * 2);
    bf16_t* LN_B = (bf16_t*)alloc((size_t)NTOK * 768 * 2);
    bf16_t* O_A  = (bf16_t*)alloc((size_t)NTOK * 768 * 2);
    bf16_t* O_B  = (bf16_t*)alloc((size_t)NTOK * 768 * 2);

    float* Xst = (float*)d_out;
    float* Sst = (float*)d_out + (size_t)NTOK * 768;

    bf16_t* SQK = arena;                               // self: [4096][1536]
    bf16_t* VTs = arena + (size_t)NTOK * 1536;         // self: [768][4096]
    bf16_t* QKx = arena;                               // cross: [4096][1536]
    bf16_t* QKs = arena + (size_t)NTOK * 1536;
    bf16_t* VxT = arena + (size_t)NTOK * 3072;         // cross: [768][4096]
    bf16_t* VsT = arena + (size_t)NTOK * 3072 + (size_t)768 * NTOK;
    bf16_t* H_A = arena;                               // mlp: [4096][3072]
    bf16_t* H_B = arena + (size_t)NTOK * 3072;

    CvtTab tab;
    const float* csrc[14] = {(const float*)d_in[2], (const float*)d_in[3],
                             (const float*)d_in[5], (const float*)d_in[6],
                             (const float*)d_in[8], (const float*)d_in[10],
                             (const float*)d_in[9], (const float*)d_in[11],
                             (const float*)d_in[12], (const float*)d_in[14],
                             (const float*)d_in[16], (const float*)d_in[18],
                             (const float*)d_in[20], (const float*)d_in[22]};
    bf16_t* cdst[14] = {bw_qkv_x, bw_proj_x, bw_qkv_s, bw_proj_s,
                        bw_cx, bw_cx + (size_t)1536 * 768,
                        bw_cs, bw_cs + (size_t)1536 * 768,
                        bw_cp, bw_cp_s, bw_mlp1, bw_mlp2, bw_mlp1s, bw_mlp2s};
    int cn[14] = {2304 * 768, 768 * 768, 2304 * 768, 768 * 768,
                  1536 * 768, 768 * 768, 1536 * 768, 768 * 768,
                  768 * 768, 768 * 768, 3072 * 768, 768 * 3072, 3072 * 768, 768 * 3072};
    for (int i = 0; i < 14; ++i) { tab.src[i] = csrc[i]; tab.dst[i] = cdst[i]; tab.n[i] = cn[i]; }
    cvt_all_kernel<<<dim3(1152, 14), 256, 0, stream>>>(tab);

    const dim3 blk(256);
    const dim3 qkv_grid(18, 32);
    const dim3 g64_grid(12, 64);
    const dim3 gelu_grid(24, 32);
    const dim3 attn_grid(16, 48);

    // ---- x self-attention ----
    ln_kernel<<<NTOK, blk, 0, stream>>>(x_in, ln1_w, ln1_b, LN_A);
    gemm_qkv_kernel<<<qkv_grid, blk, 0, stream>>>(LN_A, bw_qkv_x, SQK, VTs);
    attn_mfma_kernel<<<attn_grid, blk, 0, stream>>>(SQK, SQK + 768, VTs, O_A, 1536, 1536, 64, 64, SCALE_ATTN);
    gemm64_kernel<<<g64_grid, blk, 0, stream>>>(O_A, bw_proj_x, b_proj, x_in, Xst, 768);

    // ---- src self-attention ----
    ln_kernel<<<NTOK, blk, 0, stream>>>(src_in, ln1s_w, ln1s_b, LN_A);
    gemm_qkv_kernel<<<qkv_grid, blk, 0, stream>>>(LN_A, bw_qkv_s, SQK, VTs);
    attn_mfma_kernel<<<attn_grid, blk, 0, stream>>>(SQK, SQK + 768, VTs, O_A, 1536, 1536, 64, 64, SCALE_ATTN);
    gemm64_kernel<<<g64_grid, blk, 0, stream>>>(O_A, bw_proj_s, b_proj_s, src_in, Sst, 768);

    // ---- cross attention ----
    ln_kernel<<<NTOK, blk, 0, stream>>>(Xst, lnc_w, lnc_b, LN_A);
    ln_kernel<<<NTOK, blk, 0, stream>>>(Sst, lncs_w, lncs_b, LN_B);
    gemm_qkv_kernel<<<qkv_grid, blk, 0, stream>>>(LN_A, bw_cx, QKx, VxT);
    gemm_qkv_kernel<<<qkv_grid, blk, 0, stream>>>(LN_B, bw_cs, QKs, VsT);
    // y   = softmax(q · q_s) @ v_s
    attn_mfma_kernel<<<attn_grid, blk, 0, stream>>>(QKx, QKs, VsT, O_A, 1536, 1536, 128, 128, SCALE_ATTN);
    // y_s = softmax(k_s · kx) @ v
    attn_mfma_kernel<<<attn_grid, blk, 0, stream>>>(QKs + 64, QKx + 64, VxT, O_B, 1536, 1536, 128, 128, SCALE_ATTN);
    gemm64_kernel<<<g64_grid, blk, 0, stream>>>(O_A, bw_cp, b_cp, Xst, Xst, 768);
    gemm64_kernel<<<g64_grid, blk, 0, stream>>>(O_B, bw_cp_s, b_cp_s, Sst, Sst, 768);

    // ---- MLPs ----
    ln_kernel<<<NTOK, blk, 0, stream>>>(Xst, ln2_w, ln2_b, LN_A);
    ln_kernel<<<NTOK, blk, 0, stream>>>(Sst, ln2s_w, ln2s_b, LN_B);
    gemm_gelu_kernel<<<gelu_grid, blk, 0, stream>>>(LN_A, bw_mlp1, mlp1_b, H_A);
    gemm_gelu_kernel<<<gelu_grid, blk, 0, stream>>>(LN_B, bw_mlp1s, mlp1s_b, H_B);
    gemm64_kernel<<<g64_grid, blk, 0, stream>>>(H_A, bw_mlp2, mlp2_b, Xst, Xst, 3072);
    gemm64_kernel<<<g64_grid, blk, 0, stream>>>(H_B, bw_mlp2s, mlp2s_b, Sst, Sst, 3072);
}